// Round 1
// baseline (1491.570 us; speedup 1.0000x reference)
//
#include <hip/hip_runtime.h>
#include <hip/hip_bf16.h>

#define N_NODES 50000
#define N_EDGES 800000
#define DIM     128

// ---------------------------------------------------------------------------
// GEMM1: support = x @ W + b      (W indexed [k][d], row-major DxD)
// Tile: 32 rows x 128 cols per block, K-chunk 32, 256 threads,
// each thread computes a 4x4 micro-tile. LDS: x-tile + W-tile.
// ---------------------------------------------------------------------------
__global__ __launch_bounds__(256) void gemm_xw_bias(
    const float* __restrict__ x, const float* __restrict__ W,
    const float* __restrict__ b, float* __restrict__ out)
{
    __shared__ float xs[32][33];        // 32 rows x 32 k (+1 pad)
    __shared__ float ws[32][132];       // 32 k x 128 d (+4 pad, keeps 16B align)

    const int t    = threadIdx.x;
    const int row0 = blockIdx.x * 32;
    const int cg   = t & 31;            // col group: cols cg*4 .. cg*4+3
    const int rg   = t >> 5;            // row group: rows rg*4 .. rg*4+3

    float acc[4][4] = {};

    for (int k0 = 0; k0 < DIM; k0 += 32) {
        // ---- load x tile: one float4 per thread ----
        {
            const int r = t >> 3;           // 0..31
            const int f = t & 7;            // 0..7
            float4 v = make_float4(0.f, 0.f, 0.f, 0.f);
            if (row0 + r < N_NODES)
                v = *reinterpret_cast<const float4*>(&x[(row0 + r) * DIM + k0 + f * 4]);
            *reinterpret_cast<float4*>(&xs[r][f * 4]) = v;
        }
        // ---- load W tile: 4 float4 per thread ----
        {
            const int kr = t >> 5;          // 0..7
            const int c4 = t & 31;          // 0..31
            #pragma unroll
            for (int i = 0; i < 4; ++i) {
                const int kk = kr + i * 8;
                float4 v = *reinterpret_cast<const float4*>(&W[(k0 + kk) * DIM + c4 * 4]);
                *reinterpret_cast<float4*>(&ws[kk][c4 * 4]) = v;
            }
        }
        __syncthreads();
        #pragma unroll
        for (int k = 0; k < 32; ++k) {
            const float a0 = xs[rg * 4 + 0][k];
            const float a1 = xs[rg * 4 + 1][k];
            const float a2 = xs[rg * 4 + 2][k];
            const float a3 = xs[rg * 4 + 3][k];
            const float4 wv = *reinterpret_cast<const float4*>(&ws[k][cg * 4]);
            acc[0][0] += a0 * wv.x; acc[0][1] += a0 * wv.y; acc[0][2] += a0 * wv.z; acc[0][3] += a0 * wv.w;
            acc[1][0] += a1 * wv.x; acc[1][1] += a1 * wv.y; acc[1][2] += a1 * wv.z; acc[1][3] += a1 * wv.w;
            acc[2][0] += a2 * wv.x; acc[2][1] += a2 * wv.y; acc[2][2] += a2 * wv.z; acc[2][3] += a2 * wv.w;
            acc[3][0] += a3 * wv.x; acc[3][1] += a3 * wv.y; acc[3][2] += a3 * wv.z; acc[3][3] += a3 * wv.w;
        }
        __syncthreads();
    }

    const float4 bb = reinterpret_cast<const float4*>(b)[cg];
    #pragma unroll
    for (int i = 0; i < 4; ++i) {
        const int r = row0 + rg * 4 + i;
        if (r < N_NODES) {
            float4 o;
            o.x = acc[i][0] + bb.x;
            o.y = acc[i][1] + bb.y;
            o.z = acc[i][2] + bb.z;
            o.w = acc[i][3] + bb.w;
            *reinterpret_cast<float4*>(&out[r * DIM + cg * 4]) = o;
        }
    }
}

// ---------------------------------------------------------------------------
// Scatter-add: agg[dst[e]] += support[src[e]] * vals[e]
// One thread per (edge, float4-chunk): 32 chunks per edge.
// ---------------------------------------------------------------------------
__global__ __launch_bounds__(256) void edge_scatter(
    const float4* __restrict__ support4, const int* __restrict__ src,
    const int* __restrict__ dst, const float* __restrict__ vals,
    float* __restrict__ agg)
{
    const int idx = blockIdx.x * 256 + threadIdx.x;
    if (idx >= N_EDGES * 32) return;
    const int e = idx >> 5;
    const int q = idx & 31;
    const int s = src[e];
    const int d = dst[e];
    const float v = vals[e];
    const float4 m = support4[s * 32 + q];
    float* p = &agg[d * DIM + q * 4];
    unsafeAtomicAdd(p + 0, m.x * v);
    unsafeAtomicAdd(p + 1, m.y * v);
    unsafeAtomicAdd(p + 2, m.z * v);
    unsafeAtomicAdd(p + 3, m.w * v);
}

// ---------------------------------------------------------------------------
// GEMM2 + normalize: out = rownorm( relu(agg) @ W2^T + b2 )
// x2[n][d] = sum_k relu(agg[n][k]) * W2[d][k] + b2[d]
// Same tiling as GEMM1 but W2 loaded transposed into LDS; row L2-norm via
// shfl_xor butterfly over each 32-thread row-group.
// ---------------------------------------------------------------------------
__global__ __launch_bounds__(256) void gemm_relu_w2t_norm(
    const float* __restrict__ agg, const float* __restrict__ W2,
    const float* __restrict__ b2, float* __restrict__ out)
{
    __shared__ float xs[32][33];
    __shared__ float ws[32][132];

    const int t    = threadIdx.x;
    const int row0 = blockIdx.x * 32;
    const int cg   = t & 31;
    const int rg   = t >> 5;

    float acc[4][4] = {};

    for (int k0 = 0; k0 < DIM; k0 += 32) {
        // ---- load relu(agg) tile ----
        {
            const int r = t >> 3;
            const int f = t & 7;
            float4 v = make_float4(0.f, 0.f, 0.f, 0.f);
            if (row0 + r < N_NODES)
                v = *reinterpret_cast<const float4*>(&agg[(row0 + r) * DIM + k0 + f * 4]);
            v.x = fmaxf(v.x, 0.f); v.y = fmaxf(v.y, 0.f);
            v.z = fmaxf(v.z, 0.f); v.w = fmaxf(v.w, 0.f);
            *reinterpret_cast<float4*>(&xs[r][f * 4]) = v;
        }
        // ---- load W2 tile transposed: ws[k][d] = W2[d][k] ----
        #pragma unroll
        for (int i = 0; i < 4; ++i) {
            const int idx = t + i * 256;      // 0..1023
            const int d   = idx >> 3;         // 0..127
            const int kf  = idx & 7;          // 0..7
            float4 v = *reinterpret_cast<const float4*>(&W2[d * DIM + k0 + kf * 4]);
            ws[kf * 4 + 0][d] = v.x;
            ws[kf * 4 + 1][d] = v.y;
            ws[kf * 4 + 2][d] = v.z;
            ws[kf * 4 + 3][d] = v.w;
        }
        __syncthreads();
        #pragma unroll
        for (int k = 0; k < 32; ++k) {
            const float a0 = xs[rg * 4 + 0][k];
            const float a1 = xs[rg * 4 + 1][k];
            const float a2 = xs[rg * 4 + 2][k];
            const float a3 = xs[rg * 4 + 3][k];
            const float4 wv = *reinterpret_cast<const float4*>(&ws[k][cg * 4]);
            acc[0][0] += a0 * wv.x; acc[0][1] += a0 * wv.y; acc[0][2] += a0 * wv.z; acc[0][3] += a0 * wv.w;
            acc[1][0] += a1 * wv.x; acc[1][1] += a1 * wv.y; acc[1][2] += a1 * wv.z; acc[1][3] += a1 * wv.w;
            acc[2][0] += a2 * wv.x; acc[2][1] += a2 * wv.y; acc[2][2] += a2 * wv.z; acc[2][3] += a2 * wv.w;
            acc[3][0] += a3 * wv.x; acc[3][1] += a3 * wv.y; acc[3][2] += a3 * wv.z; acc[3][3] += a3 * wv.w;
        }
        __syncthreads();
    }

    // bias
    const float4 bb = reinterpret_cast<const float4*>(b2)[cg];
    #pragma unroll
    for (int i = 0; i < 4; ++i) {
        acc[i][0] += bb.x; acc[i][1] += bb.y; acc[i][2] += bb.z; acc[i][3] += bb.w;
    }

    // row sum of squares: butterfly across the 32 threads sharing this row group
    float p[4];
    #pragma unroll
    for (int i = 0; i < 4; ++i) {
        p[i] = acc[i][0] * acc[i][0] + acc[i][1] * acc[i][1]
             + acc[i][2] * acc[i][2] + acc[i][3] * acc[i][3];
        #pragma unroll
        for (int m = 1; m < 32; m <<= 1)
            p[i] += __shfl_xor(p[i], m);
    }

    #pragma unroll
    for (int i = 0; i < 4; ++i) {
        const int r = row0 + rg * 4 + i;
        if (r < N_NODES) {
            const float inv = 1.0f / sqrtf(p[i]);   // matches ref (0 row -> NaN, same as ref)
            float4 o;
            o.x = acc[i][0] * inv;
            o.y = acc[i][1] * inv;
            o.z = acc[i][2] * inv;
            o.w = acc[i][3] * inv;
            *reinterpret_cast<float4*>(&out[r * DIM + cg * 4]) = o;
        }
    }
}

// ---------------------------------------------------------------------------
extern "C" void kernel_launch(void* const* d_in, const int* in_sizes, int n_in,
                              void* d_out, int out_size, void* d_ws, size_t ws_size,
                              hipStream_t stream) {
    const float* x    = (const float*)d_in[0];
    const float* vals = (const float*)d_in[1];
    const float* W_gc = (const float*)d_in[2];
    const float* b_gc = (const float*)d_in[3];
    const float* W2   = (const float*)d_in[4];
    const float* b2   = (const float*)d_in[5];
    const int*   src  = (const int*)d_in[6];
    const int*   dst  = (const int*)d_in[7];

    float* support = (float*)d_out;          // temp; overwritten by final kernel
    float* agg     = (float*)d_ws;           // N*D floats = 25.6 MB scratch
    float* out     = (float*)d_out;

    const int gemm_blocks = (N_NODES + 31) / 32;   // 1563

    // support = x @ W_gc + b_gc   (staged in d_out)
    gemm_xw_bias<<<gemm_blocks, 256, 0, stream>>>(x, W_gc, b_gc, support);

    // agg = 0
    hipMemsetAsync(agg, 0, (size_t)N_NODES * DIM * sizeof(float), stream);

    // agg[dst] += support[src] * vals
    const int scatter_items = N_EDGES * 32;
    edge_scatter<<<(scatter_items + 255) / 256, 256, 0, stream>>>(
        (const float4*)support, src, dst, vals, agg);

    // out = rownorm(relu(agg) @ W2^T + b2)
    gemm_relu_w2t_norm<<<gemm_blocks, 256, 0, stream>>>(agg, W2, b2, out);
}

// Round 2
// 414.538 us; speedup vs baseline: 3.5981x; 3.5981x over previous
//
#include <hip/hip_runtime.h>
#include <hip/hip_bf16.h>

#define N_NODES 50000
#define N_EDGES 800000
#define DIM     128

// ---------------------------------------------------------------------------
// GEMM1: support = x @ W + b      (W indexed [k][d], row-major DxD)
// Tile: 32 rows x 128 cols per block, K-chunk 32, 256 threads,
// each thread computes a 4x4 micro-tile. LDS: x-tile + W-tile.
// ---------------------------------------------------------------------------
__global__ __launch_bounds__(256) void gemm_xw_bias(
    const float* __restrict__ x, const float* __restrict__ W,
    const float* __restrict__ b, float* __restrict__ out)
{
    __shared__ float xs[32][33];        // 32 rows x 32 k (+1 pad)
    __shared__ float ws[32][132];       // 32 k x 128 d (+4 pad, keeps 16B align)

    const int t    = threadIdx.x;
    const int row0 = blockIdx.x * 32;
    const int cg   = t & 31;            // col group: cols cg*4 .. cg*4+3
    const int rg   = t >> 5;            // row group: rows rg*4 .. rg*4+3

    float acc[4][4] = {};

    for (int k0 = 0; k0 < DIM; k0 += 32) {
        // ---- load x tile: one float4 per thread ----
        {
            const int r = t >> 3;           // 0..31
            const int f = t & 7;            // 0..7
            float4 v = make_float4(0.f, 0.f, 0.f, 0.f);
            if (row0 + r < N_NODES)
                v = *reinterpret_cast<const float4*>(&x[(row0 + r) * DIM + k0 + f * 4]);
            *reinterpret_cast<float4*>(&xs[r][f * 4]) = v;
        }
        // ---- load W tile: 4 float4 per thread ----
        {
            const int kr = t >> 5;          // 0..7
            const int c4 = t & 31;          // 0..31
            #pragma unroll
            for (int i = 0; i < 4; ++i) {
                const int kk = kr + i * 8;
                float4 v = *reinterpret_cast<const float4*>(&W[(k0 + kk) * DIM + c4 * 4]);
                *reinterpret_cast<float4*>(&ws[kk][c4 * 4]) = v;
            }
        }
        __syncthreads();
        #pragma unroll
        for (int k = 0; k < 32; ++k) {
            const float a0 = xs[rg * 4 + 0][k];
            const float a1 = xs[rg * 4 + 1][k];
            const float a2 = xs[rg * 4 + 2][k];
            const float a3 = xs[rg * 4 + 3][k];
            const float4 wv = *reinterpret_cast<const float4*>(&ws[k][cg * 4]);
            acc[0][0] += a0 * wv.x; acc[0][1] += a0 * wv.y; acc[0][2] += a0 * wv.z; acc[0][3] += a0 * wv.w;
            acc[1][0] += a1 * wv.x; acc[1][1] += a1 * wv.y; acc[1][2] += a1 * wv.z; acc[1][3] += a1 * wv.w;
            acc[2][0] += a2 * wv.x; acc[2][1] += a2 * wv.y; acc[2][2] += a2 * wv.z; acc[2][3] += a2 * wv.w;
            acc[3][0] += a3 * wv.x; acc[3][1] += a3 * wv.y; acc[3][2] += a3 * wv.z; acc[3][3] += a3 * wv.w;
        }
        __syncthreads();
    }

    const float4 bb = reinterpret_cast<const float4*>(b)[cg];
    #pragma unroll
    for (int i = 0; i < 4; ++i) {
        const int r = row0 + rg * 4 + i;
        if (r < N_NODES) {
            float4 o;
            o.x = acc[i][0] + bb.x;
            o.y = acc[i][1] + bb.y;
            o.z = acc[i][2] + bb.z;
            o.w = acc[i][3] + bb.w;
            *reinterpret_cast<float4*>(&out[r * DIM + cg * 4]) = o;
        }
    }
}

// ---------------------------------------------------------------------------
// CSR build step 1: histogram of dst
// ---------------------------------------------------------------------------
__global__ __launch_bounds__(256) void hist_dst(
    const int* __restrict__ dst, int* __restrict__ cnt)
{
    const int e = blockIdx.x * 256 + threadIdx.x;
    if (e < N_EDGES) atomicAdd(&cnt[dst[e]], 1);
}

// ---------------------------------------------------------------------------
// CSR build step 2: exclusive scan of counts -> offs[N+1], cur[N]
// Single block of 1024 threads; each thread owns a contiguous chunk.
// Two passes over cnt (L2-resident, 200 KB) to avoid a big register array.
// ---------------------------------------------------------------------------
__global__ __launch_bounds__(1024) void scan_offsets(
    const int* __restrict__ cnt, int* __restrict__ offs, int* __restrict__ cur)
{
    __shared__ int part[1024];
    const int t  = threadIdx.x;
    const int CH = (N_NODES + 1023) / 1024;   // 49
    const int base = t * CH;

    int s = 0;
    for (int i = 0; i < CH; ++i) {
        const int idx = base + i;
        if (idx < N_NODES) s += cnt[idx];
    }
    part[t] = s;
    __syncthreads();
    // Hillis-Steele inclusive scan over 1024 partials
    for (int off = 1; off < 1024; off <<= 1) {
        int v = 0;
        if (t >= off) v = part[t - off];
        __syncthreads();
        if (t >= off) part[t] += v;
        __syncthreads();
    }
    int run = (t == 0) ? 0 : part[t - 1];     // exclusive base for this chunk
    for (int i = 0; i < CH; ++i) {
        const int idx = base + i;
        if (idx < N_NODES) {
            offs[idx] = run;
            cur[idx]  = run;
            run += cnt[idx];
        }
    }
    if (t == 1023) offs[N_NODES] = part[1023];   // == N_EDGES
}

// ---------------------------------------------------------------------------
// CSR build step 3: reorder edges by dst into packed (src, val) pairs
// ---------------------------------------------------------------------------
__global__ __launch_bounds__(256) void reorder_edges(
    const int* __restrict__ src, const int* __restrict__ dst,
    const float* __restrict__ vals, int* __restrict__ cur,
    int2* __restrict__ packed)
{
    const int e = blockIdx.x * 256 + threadIdx.x;
    if (e >= N_EDGES) return;
    const int pos = atomicAdd(&cur[dst[e]], 1);
    packed[pos] = make_int2(src[e], __float_as_int(vals[e]));
}

// ---------------------------------------------------------------------------
// SpMM gather: one wave per destination node, lane owns 2 dims (float2).
// agg[n] = sum_{edges e with dst==n} support[src[e]] * val[e]
// Writes every row (degree-0 rows get 0) -> no memset needed.
// ---------------------------------------------------------------------------
__global__ __launch_bounds__(256) void csr_gather(
    const float2* __restrict__ support2, const int2* __restrict__ packed,
    const int* __restrict__ offs, float2* __restrict__ agg2)
{
    const int wave = (blockIdx.x * 256 + threadIdx.x) >> 6;
    const int lane = threadIdx.x & 63;
    if (wave >= N_NODES) return;
    const int beg = offs[wave];
    const int end = offs[wave + 1];

    float2 acc = make_float2(0.f, 0.f);
    int j = beg;
    // unroll-by-2 to get two independent support loads in flight
    for (; j + 1 < end; j += 2) {
        const int2 e0 = packed[j];
        const int2 e1 = packed[j + 1];
        const float2 s0 = support2[(size_t)e0.x * 64 + lane];
        const float2 s1 = support2[(size_t)e1.x * 64 + lane];
        const float v0 = __int_as_float(e0.y);
        const float v1 = __int_as_float(e1.y);
        acc.x += s0.x * v0; acc.y += s0.y * v0;
        acc.x += s1.x * v1; acc.y += s1.y * v1;
    }
    if (j < end) {
        const int2 e0 = packed[j];
        const float2 s0 = support2[(size_t)e0.x * 64 + lane];
        const float v0 = __int_as_float(e0.y);
        acc.x += s0.x * v0; acc.y += s0.y * v0;
    }
    agg2[(size_t)wave * 64 + lane] = acc;
}

// ---------------------------------------------------------------------------
// Fallback scatter (atomic) if workspace is too small for CSR buffers.
// ---------------------------------------------------------------------------
__global__ __launch_bounds__(256) void edge_scatter(
    const float4* __restrict__ support4, const int* __restrict__ src,
    const int* __restrict__ dst, const float* __restrict__ vals,
    float* __restrict__ agg)
{
    const int idx = blockIdx.x * 256 + threadIdx.x;
    if (idx >= N_EDGES * 32) return;
    const int e = idx >> 5;
    const int q = idx & 31;
    const int s = src[e];
    const int d = dst[e];
    const float v = vals[e];
    const float4 m = support4[s * 32 + q];
    float* p = &agg[d * DIM + q * 4];
    unsafeAtomicAdd(p + 0, m.x * v);
    unsafeAtomicAdd(p + 1, m.y * v);
    unsafeAtomicAdd(p + 2, m.z * v);
    unsafeAtomicAdd(p + 3, m.w * v);
}

// ---------------------------------------------------------------------------
// GEMM2 + normalize: out = rownorm( relu(agg) @ W2^T + b2 )
// ---------------------------------------------------------------------------
__global__ __launch_bounds__(256) void gemm_relu_w2t_norm(
    const float* __restrict__ agg, const float* __restrict__ W2,
    const float* __restrict__ b2, float* __restrict__ out)
{
    __shared__ float xs[32][33];
    __shared__ float ws[32][132];

    const int t    = threadIdx.x;
    const int row0 = blockIdx.x * 32;
    const int cg   = t & 31;
    const int rg   = t >> 5;

    float acc[4][4] = {};

    for (int k0 = 0; k0 < DIM; k0 += 32) {
        // ---- load relu(agg) tile ----
        {
            const int r = t >> 3;
            const int f = t & 7;
            float4 v = make_float4(0.f, 0.f, 0.f, 0.f);
            if (row0 + r < N_NODES)
                v = *reinterpret_cast<const float4*>(&agg[(row0 + r) * DIM + k0 + f * 4]);
            v.x = fmaxf(v.x, 0.f); v.y = fmaxf(v.y, 0.f);
            v.z = fmaxf(v.z, 0.f); v.w = fmaxf(v.w, 0.f);
            *reinterpret_cast<float4*>(&xs[r][f * 4]) = v;
        }
        // ---- load W2 tile transposed: ws[k][d] = W2[d][k] ----
        #pragma unroll
        for (int i = 0; i < 4; ++i) {
            const int idx = t + i * 256;      // 0..1023
            const int d   = idx >> 3;         // 0..127
            const int kf  = idx & 7;          // 0..7
            float4 v = *reinterpret_cast<const float4*>(&W2[d * DIM + k0 + kf * 4]);
            ws[kf * 4 + 0][d] = v.x;
            ws[kf * 4 + 1][d] = v.y;
            ws[kf * 4 + 2][d] = v.z;
            ws[kf * 4 + 3][d] = v.w;
        }
        __syncthreads();
        #pragma unroll
        for (int k = 0; k < 32; ++k) {
            const float a0 = xs[rg * 4 + 0][k];
            const float a1 = xs[rg * 4 + 1][k];
            const float a2 = xs[rg * 4 + 2][k];
            const float a3 = xs[rg * 4 + 3][k];
            const float4 wv = *reinterpret_cast<const float4*>(&ws[k][cg * 4]);
            acc[0][0] += a0 * wv.x; acc[0][1] += a0 * wv.y; acc[0][2] += a0 * wv.z; acc[0][3] += a0 * wv.w;
            acc[1][0] += a1 * wv.x; acc[1][1] += a1 * wv.y; acc[1][2] += a1 * wv.z; acc[1][3] += a1 * wv.w;
            acc[2][0] += a2 * wv.x; acc[2][1] += a2 * wv.y; acc[2][2] += a2 * wv.z; acc[2][3] += a2 * wv.w;
            acc[3][0] += a3 * wv.x; acc[3][1] += a3 * wv.y; acc[3][2] += a3 * wv.z; acc[3][3] += a3 * wv.w;
        }
        __syncthreads();
    }

    // bias
    const float4 bb = reinterpret_cast<const float4*>(b2)[cg];
    #pragma unroll
    for (int i = 0; i < 4; ++i) {
        acc[i][0] += bb.x; acc[i][1] += bb.y; acc[i][2] += bb.z; acc[i][3] += bb.w;
    }

    // row sum of squares: butterfly across the 32 threads sharing this row group
    float p[4];
    #pragma unroll
    for (int i = 0; i < 4; ++i) {
        p[i] = acc[i][0] * acc[i][0] + acc[i][1] * acc[i][1]
             + acc[i][2] * acc[i][2] + acc[i][3] * acc[i][3];
        #pragma unroll
        for (int m = 1; m < 32; m <<= 1)
            p[i] += __shfl_xor(p[i], m);
    }

    #pragma unroll
    for (int i = 0; i < 4; ++i) {
        const int r = row0 + rg * 4 + i;
        if (r < N_NODES) {
            const float inv = 1.0f / sqrtf(p[i]);
            float4 o;
            o.x = acc[i][0] * inv;
            o.y = acc[i][1] * inv;
            o.z = acc[i][2] * inv;
            o.w = acc[i][3] * inv;
            *reinterpret_cast<float4*>(&out[r * DIM + cg * 4]) = o;
        }
    }
}

// ---------------------------------------------------------------------------
extern "C" void kernel_launch(void* const* d_in, const int* in_sizes, int n_in,
                              void* d_out, int out_size, void* d_ws, size_t ws_size,
                              hipStream_t stream) {
    const float* x    = (const float*)d_in[0];
    const float* vals = (const float*)d_in[1];
    const float* W_gc = (const float*)d_in[2];
    const float* b_gc = (const float*)d_in[3];
    const float* W2   = (const float*)d_in[4];
    const float* b2   = (const float*)d_in[5];
    const int*   src  = (const int*)d_in[6];
    const int*   dst  = (const int*)d_in[7];

    float* support = (float*)d_out;          // temp; overwritten by final kernel
    float* out     = (float*)d_out;

    // ws layout (16B-aligned sections)
    const size_t AGG_B  = (size_t)N_NODES * DIM * sizeof(float);   // 25,600,000
    const size_t OFFS_B = 200064;                                  // (N+1)*4 padded
    const size_t CUR_B  = 200064;
    const size_t CNT_B  = 200064;
    const size_t PACK_B = (size_t)N_EDGES * 8;                     // 6,400,000
    const size_t NEED_B = AGG_B + OFFS_B + CUR_B + CNT_B + PACK_B; // ~32.6 MB

    char* wsb  = (char*)d_ws;
    float* agg = (float*)wsb;

    const int gemm_blocks = (N_NODES + 31) / 32;   // 1563

    // support = x @ W_gc + b_gc   (staged in d_out)
    gemm_xw_bias<<<gemm_blocks, 256, 0, stream>>>(x, W_gc, b_gc, support);

    if (ws_size >= NEED_B) {
        int*  offs   = (int*)(wsb + AGG_B);
        int*  cur    = (int*)(wsb + AGG_B + OFFS_B);
        int*  cnt    = (int*)(wsb + AGG_B + OFFS_B + CUR_B);
        int2* packed = (int2*)(wsb + AGG_B + OFFS_B + CUR_B + CNT_B);

        hipMemsetAsync(cnt, 0, (size_t)N_NODES * sizeof(int), stream);
        const int eb = (N_EDGES + 255) / 256;   // 3125
        hist_dst<<<eb, 256, 0, stream>>>(dst, cnt);
        scan_offsets<<<1, 1024, 0, stream>>>(cnt, offs, cur);
        reorder_edges<<<eb, 256, 0, stream>>>(src, dst, vals, cur, packed);
        // one wave per node, 4 waves per block
        const int gb = (N_NODES + 3) / 4;       // 12500
        csr_gather<<<gb, 256, 0, stream>>>(
            (const float2*)support, packed, offs, (float2*)agg);
    } else {
        // fallback: atomic scatter (round-1 path)
        hipMemsetAsync(agg, 0, AGG_B, stream);
        const int scatter_items = N_EDGES * 32;
        edge_scatter<<<(scatter_items + 255) / 256, 256, 0, stream>>>(
            (const float4*)support, src, dst, vals, agg);
    }

    // out = rownorm(relu(agg) @ W2^T + b2)
    gemm_relu_w2t_norm<<<gemm_blocks, 256, 0, stream>>>(agg, W2, b2, out);
}

// Round 3
// 302.713 us; speedup vs baseline: 4.9273x; 1.3694x over previous
//
#include <hip/hip_runtime.h>
#include <hip/hip_bf16.h>

#define N_NODES 50000
#define N_EDGES 800000
#define DIM     128
#define SCAN_BLOCKS ((N_NODES + 255) / 256)   // 196

// ---------------------------------------------------------------------------
// GEMM1: support = x @ W + b      (W indexed [k][d], row-major DxD)
// Tile: 32 rows x 128 cols per block, K-chunk 32, 256 threads,
// each thread computes a 4x4 micro-tile. LDS: x-tile + W-tile.
// ---------------------------------------------------------------------------
__global__ __launch_bounds__(256) void gemm_xw_bias(
    const float* __restrict__ x, const float* __restrict__ W,
    const float* __restrict__ b, float* __restrict__ out)
{
    __shared__ float xs[32][33];        // 32 rows x 32 k (+1 pad)
    __shared__ float ws[32][132];       // 32 k x 128 d (+4 pad, keeps 16B align)

    const int t    = threadIdx.x;
    const int row0 = blockIdx.x * 32;
    const int cg   = t & 31;            // col group: cols cg*4 .. cg*4+3
    const int rg   = t >> 5;            // row group: rows rg*4 .. rg*4+3

    float acc[4][4] = {};

    for (int k0 = 0; k0 < DIM; k0 += 32) {
        // ---- load x tile: one float4 per thread ----
        {
            const int r = t >> 3;           // 0..31
            const int f = t & 7;            // 0..7
            float4 v = make_float4(0.f, 0.f, 0.f, 0.f);
            if (row0 + r < N_NODES)
                v = *reinterpret_cast<const float4*>(&x[(row0 + r) * DIM + k0 + f * 4]);
            *reinterpret_cast<float4*>(&xs[r][f * 4]) = v;
        }
        // ---- load W tile: 4 float4 per thread ----
        {
            const int kr = t >> 5;          // 0..7
            const int c4 = t & 31;          // 0..31
            #pragma unroll
            for (int i = 0; i < 4; ++i) {
                const int kk = kr + i * 8;
                float4 v = *reinterpret_cast<const float4*>(&W[(k0 + kk) * DIM + c4 * 4]);
                *reinterpret_cast<float4*>(&ws[kk][c4 * 4]) = v;
            }
        }
        __syncthreads();
        #pragma unroll
        for (int k = 0; k < 32; ++k) {
            const float a0 = xs[rg * 4 + 0][k];
            const float a1 = xs[rg * 4 + 1][k];
            const float a2 = xs[rg * 4 + 2][k];
            const float a3 = xs[rg * 4 + 3][k];
            const float4 wv = *reinterpret_cast<const float4*>(&ws[k][cg * 4]);
            acc[0][0] += a0 * wv.x; acc[0][1] += a0 * wv.y; acc[0][2] += a0 * wv.z; acc[0][3] += a0 * wv.w;
            acc[1][0] += a1 * wv.x; acc[1][1] += a1 * wv.y; acc[1][2] += a1 * wv.z; acc[1][3] += a1 * wv.w;
            acc[2][0] += a2 * wv.x; acc[2][1] += a2 * wv.y; acc[2][2] += a2 * wv.z; acc[2][3] += a2 * wv.w;
            acc[3][0] += a3 * wv.x; acc[3][1] += a3 * wv.y; acc[3][2] += a3 * wv.z; acc[3][3] += a3 * wv.w;
        }
        __syncthreads();
    }

    const float4 bb = reinterpret_cast<const float4*>(b)[cg];
    #pragma unroll
    for (int i = 0; i < 4; ++i) {
        const int r = row0 + rg * 4 + i;
        if (r < N_NODES) {
            float4 o;
            o.x = acc[i][0] + bb.x;
            o.y = acc[i][1] + bb.y;
            o.z = acc[i][2] + bb.z;
            o.w = acc[i][3] + bb.w;
            *reinterpret_cast<float4*>(&out[r * DIM + cg * 4]) = o;
        }
    }
}

// ---------------------------------------------------------------------------
// CSR build step 1: histogram of dst
// ---------------------------------------------------------------------------
__global__ __launch_bounds__(256) void hist_dst(
    const int* __restrict__ dst, int* __restrict__ cnt)
{
    const int e = blockIdx.x * 256 + threadIdx.x;
    if (e < N_EDGES) atomicAdd(&cnt[dst[e]], 1);
}

// ---------------------------------------------------------------------------
// CSR build step 2a: per-block sums of cnt (196 blocks x 256)
// ---------------------------------------------------------------------------
__global__ __launch_bounds__(256) void block_sums(
    const int* __restrict__ cnt, int* __restrict__ bsum)
{
    __shared__ int s[256];
    const int t = threadIdx.x;
    const int i = blockIdx.x * 256 + t;
    s[t] = (i < N_NODES) ? cnt[i] : 0;
    __syncthreads();
    #pragma unroll
    for (int off = 128; off > 0; off >>= 1) {
        if (t < off) s[t] += s[t + off];
        __syncthreads();
    }
    if (t == 0) bsum[blockIdx.x] = s[0];
}

// ---------------------------------------------------------------------------
// CSR build step 2b: exclusive scan of the 196 block sums (one tiny block)
// ---------------------------------------------------------------------------
__global__ __launch_bounds__(256) void scan_bsums(
    const int* __restrict__ bsum, int* __restrict__ bbase)
{
    __shared__ int s[256];
    const int t = threadIdx.x;
    s[t] = (t < SCAN_BLOCKS) ? bsum[t] : 0;
    __syncthreads();
    #pragma unroll
    for (int off = 1; off < 256; off <<= 1) {
        int v = (t >= off) ? s[t - off] : 0;
        __syncthreads();
        s[t] += v;
        __syncthreads();
    }
    if (t < SCAN_BLOCKS) bbase[t] = (t == 0) ? 0 : s[t - 1];
}

// ---------------------------------------------------------------------------
// CSR build step 2c: per-block exclusive scan + block base -> offs, cur
// ---------------------------------------------------------------------------
__global__ __launch_bounds__(256) void scan_final(
    const int* __restrict__ cnt, const int* __restrict__ bbase,
    int* __restrict__ offs, int* __restrict__ cur)
{
    __shared__ int s[256];
    const int t = threadIdx.x;
    const int i = blockIdx.x * 256 + t;
    const int v = (i < N_NODES) ? cnt[i] : 0;
    s[t] = v;
    __syncthreads();
    #pragma unroll
    for (int off = 1; off < 256; off <<= 1) {
        int u = (t >= off) ? s[t - off] : 0;
        __syncthreads();
        s[t] += u;
        __syncthreads();
    }
    if (i < N_NODES) {
        const int ex = bbase[blockIdx.x] + s[t] - v;   // exclusive prefix
        offs[i] = ex;
        cur[i]  = ex;
    }
    if (i == N_NODES - 1) offs[N_NODES] = N_EDGES;     // total is always E
}

// ---------------------------------------------------------------------------
// CSR build step 3: reorder edges by dst into packed (src, val) pairs
// ---------------------------------------------------------------------------
__global__ __launch_bounds__(256) void reorder_edges(
    const int* __restrict__ src, const int* __restrict__ dst,
    const float* __restrict__ vals, int* __restrict__ cur,
    int2* __restrict__ packed)
{
    const int e = blockIdx.x * 256 + threadIdx.x;
    if (e >= N_EDGES) return;
    const int pos = atomicAdd(&cur[dst[e]], 1);
    packed[pos] = make_int2(src[e], __float_as_int(vals[e]));
}

// ---------------------------------------------------------------------------
// SpMM gather: one wave per destination node, lane owns 2 dims (float2).
// agg[n] = sum_{edges e with dst==n} support[src[e]] * val[e]
// Writes every row (degree-0 rows get 0) -> no memset needed.
// ---------------------------------------------------------------------------
__global__ __launch_bounds__(256) void csr_gather(
    const float2* __restrict__ support2, const int2* __restrict__ packed,
    const int* __restrict__ offs, float2* __restrict__ agg2)
{
    const int wave = (blockIdx.x * 256 + threadIdx.x) >> 6;
    const int lane = threadIdx.x & 63;
    if (wave >= N_NODES) return;
    const int beg = offs[wave];
    const int end = offs[wave + 1];

    float2 acc = make_float2(0.f, 0.f);
    int j = beg;
    // unroll-by-2 to get two independent support loads in flight
    for (; j + 1 < end; j += 2) {
        const int2 e0 = packed[j];
        const int2 e1 = packed[j + 1];
        const float2 s0 = support2[(size_t)e0.x * 64 + lane];
        const float2 s1 = support2[(size_t)e1.x * 64 + lane];
        const float v0 = __int_as_float(e0.y);
        const float v1 = __int_as_float(e1.y);
        acc.x += s0.x * v0; acc.y += s0.y * v0;
        acc.x += s1.x * v1; acc.y += s1.y * v1;
    }
    if (j < end) {
        const int2 e0 = packed[j];
        const float2 s0 = support2[(size_t)e0.x * 64 + lane];
        const float v0 = __int_as_float(e0.y);
        acc.x += s0.x * v0; acc.y += s0.y * v0;
    }
    agg2[(size_t)wave * 64 + lane] = acc;
}

// ---------------------------------------------------------------------------
// Fallback scatter (atomic) if workspace is too small for CSR buffers.
// ---------------------------------------------------------------------------
__global__ __launch_bounds__(256) void edge_scatter(
    const float4* __restrict__ support4, const int* __restrict__ src,
    const int* __restrict__ dst, const float* __restrict__ vals,
    float* __restrict__ agg)
{
    const int idx = blockIdx.x * 256 + threadIdx.x;
    if (idx >= N_EDGES * 32) return;
    const int e = idx >> 5;
    const int q = idx & 31;
    const int s = src[e];
    const int d = dst[e];
    const float v = vals[e];
    const float4 m = support4[s * 32 + q];
    float* p = &agg[d * DIM + q * 4];
    unsafeAtomicAdd(p + 0, m.x * v);
    unsafeAtomicAdd(p + 1, m.y * v);
    unsafeAtomicAdd(p + 2, m.z * v);
    unsafeAtomicAdd(p + 3, m.w * v);
}

// ---------------------------------------------------------------------------
// GEMM2 + normalize: out = rownorm( relu(agg) @ W2^T + b2 )
// ---------------------------------------------------------------------------
__global__ __launch_bounds__(256) void gemm_relu_w2t_norm(
    const float* __restrict__ agg, const float* __restrict__ W2,
    const float* __restrict__ b2, float* __restrict__ out)
{
    __shared__ float xs[32][33];
    __shared__ float ws[32][132];

    const int t    = threadIdx.x;
    const int row0 = blockIdx.x * 32;
    const int cg   = t & 31;
    const int rg   = t >> 5;

    float acc[4][4] = {};

    for (int k0 = 0; k0 < DIM; k0 += 32) {
        // ---- load relu(agg) tile ----
        {
            const int r = t >> 3;
            const int f = t & 7;
            float4 v = make_float4(0.f, 0.f, 0.f, 0.f);
            if (row0 + r < N_NODES)
                v = *reinterpret_cast<const float4*>(&agg[(row0 + r) * DIM + k0 + f * 4]);
            v.x = fmaxf(v.x, 0.f); v.y = fmaxf(v.y, 0.f);
            v.z = fmaxf(v.z, 0.f); v.w = fmaxf(v.w, 0.f);
            *reinterpret_cast<float4*>(&xs[r][f * 4]) = v;
        }
        // ---- load W2 tile transposed: ws[k][d] = W2[d][k] ----
        #pragma unroll
        for (int i = 0; i < 4; ++i) {
            const int idx = t + i * 256;      // 0..1023
            const int d   = idx >> 3;         // 0..127
            const int kf  = idx & 7;          // 0..7
            float4 v = *reinterpret_cast<const float4*>(&W2[d * DIM + k0 + kf * 4]);
            ws[kf * 4 + 0][d] = v.x;
            ws[kf * 4 + 1][d] = v.y;
            ws[kf * 4 + 2][d] = v.z;
            ws[kf * 4 + 3][d] = v.w;
        }
        __syncthreads();
        #pragma unroll
        for (int k = 0; k < 32; ++k) {
            const float a0 = xs[rg * 4 + 0][k];
            const float a1 = xs[rg * 4 + 1][k];
            const float a2 = xs[rg * 4 + 2][k];
            const float a3 = xs[rg * 4 + 3][k];
            const float4 wv = *reinterpret_cast<const float4*>(&ws[k][cg * 4]);
            acc[0][0] += a0 * wv.x; acc[0][1] += a0 * wv.y; acc[0][2] += a0 * wv.z; acc[0][3] += a0 * wv.w;
            acc[1][0] += a1 * wv.x; acc[1][1] += a1 * wv.y; acc[1][2] += a1 * wv.z; acc[1][3] += a1 * wv.w;
            acc[2][0] += a2 * wv.x; acc[2][1] += a2 * wv.y; acc[2][2] += a2 * wv.z; acc[2][3] += a2 * wv.w;
            acc[3][0] += a3 * wv.x; acc[3][1] += a3 * wv.y; acc[3][2] += a3 * wv.z; acc[3][3] += a3 * wv.w;
        }
        __syncthreads();
    }

    // bias
    const float4 bb = reinterpret_cast<const float4*>(b2)[cg];
    #pragma unroll
    for (int i = 0; i < 4; ++i) {
        acc[i][0] += bb.x; acc[i][1] += bb.y; acc[i][2] += bb.z; acc[i][3] += bb.w;
    }

    // row sum of squares: butterfly across the 32 threads sharing this row group
    float p[4];
    #pragma unroll
    for (int i = 0; i < 4; ++i) {
        p[i] = acc[i][0] * acc[i][0] + acc[i][1] * acc[i][1]
             + acc[i][2] * acc[i][2] + acc[i][3] * acc[i][3];
        #pragma unroll
        for (int m = 1; m < 32; m <<= 1)
            p[i] += __shfl_xor(p[i], m);
    }

    #pragma unroll
    for (int i = 0; i < 4; ++i) {
        const int r = row0 + rg * 4 + i;
        if (r < N_NODES) {
            const float inv = 1.0f / sqrtf(p[i]);
            float4 o;
            o.x = acc[i][0] * inv;
            o.y = acc[i][1] * inv;
            o.z = acc[i][2] * inv;
            o.w = acc[i][3] * inv;
            *reinterpret_cast<float4*>(&out[r * DIM + cg * 4]) = o;
        }
    }
}

// ---------------------------------------------------------------------------
extern "C" void kernel_launch(void* const* d_in, const int* in_sizes, int n_in,
                              void* d_out, int out_size, void* d_ws, size_t ws_size,
                              hipStream_t stream) {
    const float* x    = (const float*)d_in[0];
    const float* vals = (const float*)d_in[1];
    const float* W_gc = (const float*)d_in[2];
    const float* b_gc = (const float*)d_in[3];
    const float* W2   = (const float*)d_in[4];
    const float* b2   = (const float*)d_in[5];
    const int*   src  = (const int*)d_in[6];
    const int*   dst  = (const int*)d_in[7];

    float* support = (float*)d_out;          // temp; overwritten by final kernel
    float* out     = (float*)d_out;

    // ws layout (16B-aligned sections)
    const size_t AGG_B  = (size_t)N_NODES * DIM * sizeof(float);   // 25,600,000
    const size_t OFFS_B = 200064;                                  // (N+1)*4 padded
    const size_t CUR_B  = 200064;
    const size_t CNT_B  = 200064;
    const size_t BS_B   = 4096;                                    // bsum+bbase
    const size_t PACK_B = (size_t)N_EDGES * 8;                     // 6,400,000
    const size_t NEED_B = AGG_B + OFFS_B + CUR_B + CNT_B + BS_B + PACK_B;

    char* wsb  = (char*)d_ws;
    float* agg = (float*)wsb;

    const int gemm_blocks = (N_NODES + 31) / 32;   // 1563

    // support = x @ W_gc + b_gc   (staged in d_out)
    gemm_xw_bias<<<gemm_blocks, 256, 0, stream>>>(x, W_gc, b_gc, support);

    if (ws_size >= NEED_B) {
        int*  offs   = (int*)(wsb + AGG_B);
        int*  cur    = (int*)(wsb + AGG_B + OFFS_B);
        int*  cnt    = (int*)(wsb + AGG_B + OFFS_B + CUR_B);
        int*  bsum   = (int*)(wsb + AGG_B + OFFS_B + CUR_B + CNT_B);
        int*  bbase  = bsum + 512;
        int2* packed = (int2*)(wsb + AGG_B + OFFS_B + CUR_B + CNT_B + BS_B);

        hipMemsetAsync(cnt, 0, (size_t)N_NODES * sizeof(int), stream);
        const int eb = (N_EDGES + 255) / 256;   // 3125
        hist_dst<<<eb, 256, 0, stream>>>(dst, cnt);
        block_sums<<<SCAN_BLOCKS, 256, 0, stream>>>(cnt, bsum);
        scan_bsums<<<1, 256, 0, stream>>>(bsum, bbase);
        scan_final<<<SCAN_BLOCKS, 256, 0, stream>>>(cnt, bbase, offs, cur);
        reorder_edges<<<eb, 256, 0, stream>>>(src, dst, vals, cur, packed);
        // one wave per node, 4 waves per block
        const int gb = (N_NODES + 3) / 4;       // 12500
        csr_gather<<<gb, 256, 0, stream>>>(
            (const float2*)support, packed, offs, (float2*)agg);
    } else {
        // fallback: atomic scatter (round-1 path)
        hipMemsetAsync(agg, 0, AGG_B, stream);
        const int scatter_items = N_EDGES * 32;
        edge_scatter<<<(scatter_items + 255) / 256, 256, 0, stream>>>(
            (const float4*)support, src, dst, vals, agg);
    }

    // out = rownorm(relu(agg) @ W2^T + b2)
    gemm_relu_w2t_norm<<<gemm_blocks, 256, 0, stream>>>(agg, W2, b2, out);
}

// Round 4
// 244.894 us; speedup vs baseline: 6.0907x; 1.2361x over previous
//
#include <hip/hip_runtime.h>
#include <hip/hip_bf16.h>

#define N_NODES 50000
#define N_EDGES 800000
#define DIM     128
#define N_STRIPS (N_NODES / 16)               // 3125 exact: 16-row strips
#define SCAN_BLOCKS ((N_NODES + 255) / 256)   // 196

typedef short short8 __attribute__((ext_vector_type(8)));
typedef float floatx4 __attribute__((ext_vector_type(4)));

// fp32 -> bf16 (RNE) bit pattern
__device__ inline unsigned short f2bf(float f) {
    __hip_bfloat16 h = __float2bfloat16(f);
    return *reinterpret_cast<unsigned short*>(&h);
}

// ---------------------------------------------------------------------------
// Pack W (for GEMM1, B[k][n] = W[k][n]) and W2 (for GEMM2, B[k][n] = W2[n][k])
// into MFMA B-fragment order, bf16:
//   slot s = (ks*8 + nt)*64 + lane holds 8 bf16: B[ks*32 + (lane>>4)*8 + j][nt*16 + (lane&15)]
// 16 blocks x 256: blocks 0-7 pack W, 8-15 pack W2. One 16B slot per thread.
// ---------------------------------------------------------------------------
__global__ __launch_bounds__(256) void pack_weights(
    const float* __restrict__ W, const float* __restrict__ W2,
    uint4* __restrict__ p1, uint4* __restrict__ p2)
{
    const int s    = (blockIdx.x & 7) * 256 + threadIdx.x;   // 0..2047
    const int lane = s & 63;
    const int nt   = (s >> 6) & 7;
    const int ks   = s >> 9;
    const int m    = lane & 15;
    const int q    = lane >> 4;

    unsigned short e[8];
    if (blockIdx.x < 8) {
        // B = W (row-major [k][d]); column-strided reads, L2-resident, one-shot
        #pragma unroll
        for (int j = 0; j < 8; ++j)
            e[j] = f2bf(W[(ks * 32 + q * 8 + j) * DIM + nt * 16 + m]);
        uint4 o;
        o.x = (unsigned)e[0] | ((unsigned)e[1] << 16);
        o.y = (unsigned)e[2] | ((unsigned)e[3] << 16);
        o.z = (unsigned)e[4] | ((unsigned)e[5] << 16);
        o.w = (unsigned)e[6] | ((unsigned)e[7] << 16);
        p1[s] = o;
    } else {
        // B = W2^T: 8 consecutive floats from W2 row
        const float4 f0 = *reinterpret_cast<const float4*>(&W2[(nt * 16 + m) * DIM + ks * 32 + q * 8]);
        const float4 f1 = *reinterpret_cast<const float4*>(&W2[(nt * 16 + m) * DIM + ks * 32 + q * 8 + 4]);
        e[0] = f2bf(f0.x); e[1] = f2bf(f0.y); e[2] = f2bf(f0.z); e[3] = f2bf(f0.w);
        e[4] = f2bf(f1.x); e[5] = f2bf(f1.y); e[6] = f2bf(f1.z); e[7] = f2bf(f1.w);
        uint4 o;
        o.x = (unsigned)e[0] | ((unsigned)e[1] << 16);
        o.y = (unsigned)e[2] | ((unsigned)e[3] << 16);
        o.z = (unsigned)e[4] | ((unsigned)e[5] << 16);
        o.w = (unsigned)e[6] | ((unsigned)e[7] << 16);
        p2[s] = o;
    }
}

// ---------------------------------------------------------------------------
// GEMM1 (MFMA, no LDS): support_bf16 = bf16( x @ W + b )
// One wave per 16-row strip; 4 waves/block. A loaded from global fp32 and
// converted in-register; B fragments loaded pre-packed from L2.
// MFMA 16x16x32: A[m=lane&15][k=(lane>>4)*8+j], C/D col=lane&15, row=(lane>>4)*4+i.
// ---------------------------------------------------------------------------
__global__ __launch_bounds__(256) void gemm1_mfma(
    const float* __restrict__ x, const short8* __restrict__ Bp,
    const float* __restrict__ bias, unsigned short* __restrict__ support)
{
    const int wave  = threadIdx.x >> 6;
    const int lane  = threadIdx.x & 63;
    const int strip = blockIdx.x * 4 + wave;
    if (strip >= N_STRIPS) return;
    const int m = lane & 15;
    const int q = lane >> 4;
    const int row = strip * 16 + m;

    // A fragments: 4 k-steps, 8 fp32 each -> bf16
    short8 a[4];
    const float4* xr = reinterpret_cast<const float4*>(&x[(size_t)row * DIM]);
    #pragma unroll
    for (int ks = 0; ks < 4; ++ks) {
        const float4 f0 = xr[ks * 8 + q * 2];
        const float4 f1 = xr[ks * 8 + q * 2 + 1];
        short8 t;
        t[0] = (short)f2bf(f0.x); t[1] = (short)f2bf(f0.y);
        t[2] = (short)f2bf(f0.z); t[3] = (short)f2bf(f0.w);
        t[4] = (short)f2bf(f1.x); t[5] = (short)f2bf(f1.y);
        t[6] = (short)f2bf(f1.z); t[7] = (short)f2bf(f1.w);
        a[ks] = t;
    }

    floatx4 acc[8];
    #pragma unroll
    for (int nt = 0; nt < 8; ++nt) { acc[nt][0] = 0.f; acc[nt][1] = 0.f; acc[nt][2] = 0.f; acc[nt][3] = 0.f; }

    #pragma unroll
    for (int ks = 0; ks < 4; ++ks) {
        #pragma unroll
        for (int nt = 0; nt < 8; ++nt) {
            const short8 bf = Bp[(ks * 8 + nt) * 64 + lane];
            acc[nt] = __builtin_amdgcn_mfma_f32_16x16x32_bf16(a[ks], bf, acc[nt], 0, 0, 0);
        }
    }

    #pragma unroll
    for (int nt = 0; nt < 8; ++nt) {
        const float bb = bias[nt * 16 + m];
        #pragma unroll
        for (int i = 0; i < 4; ++i) {
            const int r = strip * 16 + q * 4 + i;
            support[(size_t)r * DIM + nt * 16 + m] = f2bf(acc[nt][i] + bb);
        }
    }
}

// ---------------------------------------------------------------------------
// CSR build: histogram of dst
// ---------------------------------------------------------------------------
__global__ __launch_bounds__(256) void hist_dst(
    const int* __restrict__ dst, int* __restrict__ cnt)
{
    const int e = blockIdx.x * 256 + threadIdx.x;
    if (e < N_EDGES) atomicAdd(&cnt[dst[e]], 1);
}

// ---------------------------------------------------------------------------
// CSR build: hierarchical exclusive scan (block sums -> scan sums -> final)
// ---------------------------------------------------------------------------
__global__ __launch_bounds__(256) void block_sums(
    const int* __restrict__ cnt, int* __restrict__ bsum)
{
    __shared__ int s[256];
    const int t = threadIdx.x;
    const int i = blockIdx.x * 256 + t;
    s[t] = (i < N_NODES) ? cnt[i] : 0;
    __syncthreads();
    #pragma unroll
    for (int off = 128; off > 0; off >>= 1) {
        if (t < off) s[t] += s[t + off];
        __syncthreads();
    }
    if (t == 0) bsum[blockIdx.x] = s[0];
}

__global__ __launch_bounds__(256) void scan_bsums(
    const int* __restrict__ bsum, int* __restrict__ bbase)
{
    __shared__ int s[256];
    const int t = threadIdx.x;
    s[t] = (t < SCAN_BLOCKS) ? bsum[t] : 0;
    __syncthreads();
    #pragma unroll
    for (int off = 1; off < 256; off <<= 1) {
        int v = (t >= off) ? s[t - off] : 0;
        __syncthreads();
        s[t] += v;
        __syncthreads();
    }
    if (t < SCAN_BLOCKS) bbase[t] = (t == 0) ? 0 : s[t - 1];
}

__global__ __launch_bounds__(256) void scan_final(
    const int* __restrict__ cnt, const int* __restrict__ bbase,
    int* __restrict__ offs, int* __restrict__ cur)
{
    __shared__ int s[256];
    const int t = threadIdx.x;
    const int i = blockIdx.x * 256 + t;
    const int v = (i < N_NODES) ? cnt[i] : 0;
    s[t] = v;
    __syncthreads();
    #pragma unroll
    for (int off = 1; off < 256; off <<= 1) {
        int u = (t >= off) ? s[t - off] : 0;
        __syncthreads();
        s[t] += u;
        __syncthreads();
    }
    if (i < N_NODES) {
        const int ex = bbase[blockIdx.x] + s[t] - v;
        offs[i] = ex;
        cur[i]  = ex;
    }
    if (i == N_NODES - 1) offs[N_NODES] = N_EDGES;
}

// ---------------------------------------------------------------------------
// CSR build: reorder edges by dst into packed (src, val)
// ---------------------------------------------------------------------------
__global__ __launch_bounds__(256) void reorder_edges(
    const int* __restrict__ src, const int* __restrict__ dst,
    const float* __restrict__ vals, int* __restrict__ cur,
    int2* __restrict__ packed)
{
    const int e = blockIdx.x * 256 + threadIdx.x;
    if (e >= N_EDGES) return;
    const int pos = atomicAdd(&cur[dst[e]], 1);
    packed[pos] = make_int2(src[e], __float_as_int(vals[e]));
}

// ---------------------------------------------------------------------------
// SpMM gather (bf16 support): one wave per dst node, lane owns 2 dims (1 uint).
// Applies relu, stores agg as bf16 (feeds GEMM2 A-fragments directly).
// ---------------------------------------------------------------------------
__global__ __launch_bounds__(256) void csr_gather_bf16(
    const unsigned int* __restrict__ sup, const int2* __restrict__ packed,
    const int* __restrict__ offs, unsigned int* __restrict__ agg)
{
    const int node = (blockIdx.x * 256 + threadIdx.x) >> 6;
    const int lane = threadIdx.x & 63;
    if (node >= N_NODES) return;
    const int beg = offs[node];
    const int end = offs[node + 1];

    float ax = 0.f, ay = 0.f;
    int j = beg;
    for (; j + 3 < end; j += 4) {
        const int2 e0 = packed[j];
        const int2 e1 = packed[j + 1];
        const int2 e2 = packed[j + 2];
        const int2 e3 = packed[j + 3];
        const unsigned int u0 = sup[(size_t)e0.x * 64 + lane];
        const unsigned int u1 = sup[(size_t)e1.x * 64 + lane];
        const unsigned int u2 = sup[(size_t)e2.x * 64 + lane];
        const unsigned int u3 = sup[(size_t)e3.x * 64 + lane];
        const float v0 = __int_as_float(e0.y);
        const float v1 = __int_as_float(e1.y);
        const float v2 = __int_as_float(e2.y);
        const float v3 = __int_as_float(e3.y);
        ax += __uint_as_float(u0 << 16) * v0;          ay += __uint_as_float(u0 & 0xffff0000u) * v0;
        ax += __uint_as_float(u1 << 16) * v1;          ay += __uint_as_float(u1 & 0xffff0000u) * v1;
        ax += __uint_as_float(u2 << 16) * v2;          ay += __uint_as_float(u2 & 0xffff0000u) * v2;
        ax += __uint_as_float(u3 << 16) * v3;          ay += __uint_as_float(u3 & 0xffff0000u) * v3;
    }
    for (; j < end; ++j) {
        const int2 e0 = packed[j];
        const unsigned int u0 = sup[(size_t)e0.x * 64 + lane];
        const float v0 = __int_as_float(e0.y);
        ax += __uint_as_float(u0 << 16) * v0;
        ay += __uint_as_float(u0 & 0xffff0000u) * v0;
    }
    ax = fmaxf(ax, 0.f);   // relu folded in (bf16 quantize after relu)
    ay = fmaxf(ay, 0.f);
    agg[(size_t)node * 64 + lane] = (unsigned int)f2bf(ax) | ((unsigned int)f2bf(ay) << 16);
}

// ---------------------------------------------------------------------------
// GEMM2 (MFMA, no LDS) + row L2-normalize:
// out = rownorm( agg_bf16 @ W2^T + b2 ),  agg already relu'd.
// ---------------------------------------------------------------------------
__global__ __launch_bounds__(256) void gemm2_mfma(
    const short8* __restrict__ aggv, const short8* __restrict__ Bp,
    const float* __restrict__ bias, float* __restrict__ out)
{
    const int wave  = threadIdx.x >> 6;
    const int lane  = threadIdx.x & 63;
    const int strip = blockIdx.x * 4 + wave;
    if (strip >= N_STRIPS) return;
    const int m = lane & 15;
    const int q = lane >> 4;
    const int row = strip * 16 + m;

    short8 a[4];
    #pragma unroll
    for (int ks = 0; ks < 4; ++ks)
        a[ks] = aggv[(size_t)row * (DIM / 8) + ks * 4 + q];   // 8 bf16 = 16B aligned

    floatx4 acc[8];
    #pragma unroll
    for (int nt = 0; nt < 8; ++nt) { acc[nt][0] = 0.f; acc[nt][1] = 0.f; acc[nt][2] = 0.f; acc[nt][3] = 0.f; }

    #pragma unroll
    for (int ks = 0; ks < 4; ++ks) {
        #pragma unroll
        for (int nt = 0; nt < 8; ++nt) {
            const short8 bf = Bp[(ks * 8 + nt) * 64 + lane];
            acc[nt] = __builtin_amdgcn_mfma_f32_16x16x32_bf16(a[ks], bf, acc[nt], 0, 0, 0);
        }
    }

    // bias (col = nt*16 + m)
    #pragma unroll
    for (int nt = 0; nt < 8; ++nt) {
        const float bb = bias[nt * 16 + m];
        #pragma unroll
        for (int i = 0; i < 4; ++i) acc[nt][i] += bb;
    }

    // row sums of squares: rows (q*4+i) live across the 16 lanes of group q
    float sq[4] = {0.f, 0.f, 0.f, 0.f};
    #pragma unroll
    for (int nt = 0; nt < 8; ++nt)
        #pragma unroll
        for (int i = 0; i < 4; ++i) sq[i] += acc[nt][i] * acc[nt][i];
    #pragma unroll
    for (int i = 0; i < 4; ++i) {
        #pragma unroll
        for (int mask = 1; mask < 16; mask <<= 1)
            sq[i] += __shfl_xor(sq[i], mask);
        sq[i] = 1.0f / sqrtf(sq[i]);
    }

    #pragma unroll
    for (int nt = 0; nt < 8; ++nt) {
        #pragma unroll
        for (int i = 0; i < 4; ++i) {
            const int r = strip * 16 + q * 4 + i;
            out[(size_t)r * DIM + nt * 16 + m] = acc[nt][i] * sq[i];
        }
    }
}

// ---------------------------------------------------------------------------
extern "C" void kernel_launch(void* const* d_in, const int* in_sizes, int n_in,
                              void* d_out, int out_size, void* d_ws, size_t ws_size,
                              hipStream_t stream) {
    const float* x    = (const float*)d_in[0];
    const float* vals = (const float*)d_in[1];
    const float* W_gc = (const float*)d_in[2];
    const float* b_gc = (const float*)d_in[3];
    const float* W2   = (const float*)d_in[4];
    const float* b2   = (const float*)d_in[5];
    const int*   src  = (const int*)d_in[6];
    const int*   dst  = (const int*)d_in[7];

    // support (bf16, 12.8 MB) staged in d_out; final fp32 out overwrites it.
    unsigned short* support = (unsigned short*)d_out;
    float* out = (float*)d_out;

    // ws layout (all 16B-aligned)
    const size_t AGG_B  = (size_t)N_NODES * DIM * 2;   // 12,800,000 (bf16)
    const size_t OFFS_B = 200064;
    const size_t CUR_B  = 200064;
    const size_t CNT_B  = 200064;
    const size_t BS_B   = 4096;
    const size_t PACK_B = (size_t)N_EDGES * 8;         // 6,400,000
    const size_t PW_B   = 32768;                        // each packed weight

    char* wsb = (char*)d_ws;
    unsigned int* agg    = (unsigned int*)wsb;
    int*   offs   = (int*)(wsb + AGG_B);
    int*   cur    = (int*)(wsb + AGG_B + OFFS_B);
    int*   cnt    = (int*)(wsb + AGG_B + OFFS_B + CUR_B);
    int*   bsum   = (int*)(wsb + AGG_B + OFFS_B + CUR_B + CNT_B);
    int*   bbase  = bsum + 512;
    int2*  packed = (int2*)(wsb + AGG_B + OFFS_B + CUR_B + CNT_B + BS_B);
    uint4* pw1    = (uint4*)(wsb + AGG_B + OFFS_B + CUR_B + CNT_B + BS_B + PACK_B);
    uint4* pw2    = (uint4*)(wsb + AGG_B + OFFS_B + CUR_B + CNT_B + BS_B + PACK_B + PW_B);

    const int eb = (N_EDGES + 255) / 256;          // 3125
    const int gb = (N_STRIPS + 3) / 4;             // 782 gemm blocks

    // pack W and W2 into MFMA B-fragment order (bf16)
    pack_weights<<<16, 256, 0, stream>>>(W_gc, W2, pw1, pw2);

    // support = bf16(x @ W_gc + b_gc)
    gemm1_mfma<<<gb, 256, 0, stream>>>(x, (const short8*)pw1, b_gc, support);

    // CSR build
    hipMemsetAsync(cnt, 0, (size_t)N_NODES * sizeof(int), stream);
    hist_dst<<<eb, 256, 0, stream>>>(dst, cnt);
    block_sums<<<SCAN_BLOCKS, 256, 0, stream>>>(cnt, bsum);
    scan_bsums<<<1, 256, 0, stream>>>(bsum, bbase);
    scan_final<<<SCAN_BLOCKS, 256, 0, stream>>>(cnt, bbase, offs, cur);
    reorder_edges<<<eb, 256, 0, stream>>>(src, dst, vals, cur, packed);

    // agg = bf16(relu(segment_sum(support[src]*val, dst)))
    csr_gather_bf16<<<(N_NODES * 64 + 255) / 256, 256, 0, stream>>>(
        (const unsigned int*)support, packed, offs, agg);

    // out = rownorm(agg @ W2^T + b2)
    gemm2_mfma<<<gb, 256, 0, stream>>>(
        (const short8*)agg, (const short8*)pw2, b2, out);
}

// Round 5
// 191.687 us; speedup vs baseline: 7.7813x; 1.2776x over previous
//
#include <hip/hip_runtime.h>
#include <hip/hip_bf16.h>

#define N_NODES 50000
#define N_EDGES 800000
#define DIM     128
#define N_STRIPS (N_NODES / 16)               // 3125 exact: 16-row strips
#define N_BKT    ((N_NODES + 255) / 256)      // 196 buckets (dst >> 8)
#define EDGE_BLOCKS ((N_EDGES + 4095) / 4096) // 196 chunks of 4096 edges
#define BUF_CAP  6144                          // LDS edge buffer (mean 4082, 32 sigma)

typedef short short8 __attribute__((ext_vector_type(8)));
typedef float floatx4 __attribute__((ext_vector_type(4)));

// fp32 -> bf16 (RNE) bit pattern
__device__ inline unsigned short f2bf(float f) {
    __hip_bfloat16 h = __float2bfloat16(f);
    return *reinterpret_cast<unsigned short*>(&h);
}

// ---------------------------------------------------------------------------
// Pack W (GEMM1, B[k][n]=W[k][n]) and W2 (GEMM2, B[k][n]=W2[n][k]) into MFMA
// B-fragment order, bf16. slot s=(ks*8+nt)*64+lane holds 8 bf16:
//   B[ks*32 + (lane>>4)*8 + j][nt*16 + (lane&15)]
// ---------------------------------------------------------------------------
__global__ __launch_bounds__(256) void pack_weights(
    const float* __restrict__ W, const float* __restrict__ W2,
    uint4* __restrict__ p1, uint4* __restrict__ p2)
{
    const int s    = (blockIdx.x & 7) * 256 + threadIdx.x;   // 0..2047
    const int lane = s & 63;
    const int nt   = (s >> 6) & 7;
    const int ks   = s >> 9;
    const int m    = lane & 15;
    const int q    = lane >> 4;

    unsigned short e[8];
    if (blockIdx.x < 8) {
        #pragma unroll
        for (int j = 0; j < 8; ++j)
            e[j] = f2bf(W[(ks * 32 + q * 8 + j) * DIM + nt * 16 + m]);
        uint4 o;
        o.x = (unsigned)e[0] | ((unsigned)e[1] << 16);
        o.y = (unsigned)e[2] | ((unsigned)e[3] << 16);
        o.z = (unsigned)e[4] | ((unsigned)e[5] << 16);
        o.w = (unsigned)e[6] | ((unsigned)e[7] << 16);
        p1[s] = o;
    } else {
        const float4 f0 = *reinterpret_cast<const float4*>(&W2[(nt * 16 + m) * DIM + ks * 32 + q * 8]);
        const float4 f1 = *reinterpret_cast<const float4*>(&W2[(nt * 16 + m) * DIM + ks * 32 + q * 8 + 4]);
        e[0] = f2bf(f0.x); e[1] = f2bf(f0.y); e[2] = f2bf(f0.z); e[3] = f2bf(f0.w);
        e[4] = f2bf(f1.x); e[5] = f2bf(f1.y); e[6] = f2bf(f1.z); e[7] = f2bf(f1.w);
        uint4 o;
        o.x = (unsigned)e[0] | ((unsigned)e[1] << 16);
        o.y = (unsigned)e[2] | ((unsigned)e[3] << 16);
        o.z = (unsigned)e[4] | ((unsigned)e[5] << 16);
        o.w = (unsigned)e[6] | ((unsigned)e[7] << 16);
        p2[s] = o;
    }
}

// ---------------------------------------------------------------------------
// GEMM1 (MFMA, no LDS): support_bf16 = bf16( x @ W + b )
// ---------------------------------------------------------------------------
__global__ __launch_bounds__(256) void gemm1_mfma(
    const float* __restrict__ x, const short8* __restrict__ Bp,
    const float* __restrict__ bias, unsigned short* __restrict__ support)
{
    const int wave  = threadIdx.x >> 6;
    const int lane  = threadIdx.x & 63;
    const int strip = blockIdx.x * 4 + wave;
    if (strip >= N_STRIPS) return;
    const int m = lane & 15;
    const int q = lane >> 4;
    const int row = strip * 16 + m;

    short8 a[4];
    const float4* xr = reinterpret_cast<const float4*>(&x[(size_t)row * DIM]);
    #pragma unroll
    for (int ks = 0; ks < 4; ++ks) {
        const float4 f0 = xr[ks * 8 + q * 2];
        const float4 f1 = xr[ks * 8 + q * 2 + 1];
        short8 t;
        t[0] = (short)f2bf(f0.x); t[1] = (short)f2bf(f0.y);
        t[2] = (short)f2bf(f0.z); t[3] = (short)f2bf(f0.w);
        t[4] = (short)f2bf(f1.x); t[5] = (short)f2bf(f1.y);
        t[6] = (short)f2bf(f1.z); t[7] = (short)f2bf(f1.w);
        a[ks] = t;
    }

    floatx4 acc[8];
    #pragma unroll
    for (int nt = 0; nt < 8; ++nt) { acc[nt][0] = 0.f; acc[nt][1] = 0.f; acc[nt][2] = 0.f; acc[nt][3] = 0.f; }

    #pragma unroll
    for (int ks = 0; ks < 4; ++ks) {
        #pragma unroll
        for (int nt = 0; nt < 8; ++nt) {
            const short8 bf = Bp[(ks * 8 + nt) * 64 + lane];
            acc[nt] = __builtin_amdgcn_mfma_f32_16x16x32_bf16(a[ks], bf, acc[nt], 0, 0, 0);
        }
    }

    #pragma unroll
    for (int nt = 0; nt < 8; ++nt) {
        const float bb = bias[nt * 16 + m];
        #pragma unroll
        for (int i = 0; i < 4; ++i) {
            const int r = strip * 16 + q * 4 + i;
            support[(size_t)r * DIM + nt * 16 + m] = f2bf(acc[nt][i] + bb);
        }
    }
}

// ---------------------------------------------------------------------------
// CSR build pass 1: bucket histogram (bucket = dst>>8), block-aggregated.
// 196 blocks x 4096 edges; 196 global atomics per block.
// ---------------------------------------------------------------------------
__global__ __launch_bounds__(256) void bucket_hist(
    const int* __restrict__ dst, int* __restrict__ bcnt)
{
    __shared__ int bh[256];
    const int t = threadIdx.x;
    bh[t] = 0;
    __syncthreads();
    const int base = blockIdx.x * 4096;
    #pragma unroll
    for (int i = 0; i < 16; ++i) {
        const int e = base + t + i * 256;
        if (e < N_EDGES) atomicAdd(&bh[dst[e] >> 8], 1);
    }
    __syncthreads();
    if (t < N_BKT && bh[t]) atomicAdd(&bcnt[t], bh[t]);
}

// ---------------------------------------------------------------------------
// CSR build pass 2: scan 196 bucket counts -> bbase[197], gbcur[196]
// ---------------------------------------------------------------------------
__global__ __launch_bounds__(256) void scan_buckets(
    const int* __restrict__ bcnt, int* __restrict__ bbase, int* __restrict__ gbcur)
{
    __shared__ int s[256];
    const int t = threadIdx.x;
    const int v = (t < N_BKT) ? bcnt[t] : 0;
    s[t] = v;
    __syncthreads();
    #pragma unroll
    for (int off = 1; off < 256; off <<= 1) {
        int u = (t >= off) ? s[t - off] : 0;
        __syncthreads();
        s[t] += u;
        __syncthreads();
    }
    if (t < N_BKT) {
        const int ex = s[t] - v;
        bbase[t] = ex;
        gbcur[t] = ex;
    }
    if (t == 0) bbase[N_BKT] = N_EDGES;
}

// ---------------------------------------------------------------------------
// CSR build pass 3: block-aggregated scatter into bucket regions.
// Each block reserves one run per bucket -> writes land in ~21-edge
// contiguous runs (write-amplification killer vs per-edge random scatter).
// Payload: word0 = src | (dst&0xFF)<<16, word1 = val bits.
// ---------------------------------------------------------------------------
__global__ __launch_bounds__(256) void bucket_scatter(
    const int* __restrict__ src, const int* __restrict__ dst,
    const float* __restrict__ vals, int* __restrict__ gbcur,
    int2* __restrict__ bucketed)
{
    __shared__ int bh[256];
    __shared__ int rcur[256];
    const int t = threadIdx.x;
    bh[t] = 0;
    __syncthreads();
    const int base = blockIdx.x * 4096;
    #pragma unroll
    for (int i = 0; i < 16; ++i) {
        const int e = base + t + i * 256;
        if (e < N_EDGES) atomicAdd(&bh[dst[e] >> 8], 1);
    }
    __syncthreads();
    if (t < N_BKT) rcur[t] = bh[t] ? atomicAdd(&gbcur[t], bh[t]) : 0;
    __syncthreads();
    #pragma unroll
    for (int i = 0; i < 16; ++i) {
        const int e = base + t + i * 256;
        if (e < N_EDGES) {
            const int d = dst[e];
            const int pos = atomicAdd(&rcur[d >> 8], 1);
            bucketed[pos] = make_int2((src[e] & 0xFFFF) | ((d & 0xFF) << 16),
                                      __float_as_int(vals[e]));
        }
    }
}

// ---------------------------------------------------------------------------
// CSR build pass 4: one block per bucket. Per-node count + scan in LDS,
// scatter into LDS buffer, coalesced linear write to packed; emits offs.
// Subsumes the per-node histogram and all scan kernels.
// ---------------------------------------------------------------------------
__global__ __launch_bounds__(256) void bucket_to_csr(
    const int2* __restrict__ bucketed, const int* __restrict__ bbase,
    int2* __restrict__ packed, int* __restrict__ offs)
{
    __shared__ int cnt[256];
    __shared__ int sc[256];
    __shared__ int lcur[256];
    __shared__ int2 buf[BUF_CAP];

    const int b    = blockIdx.x;
    const int t    = threadIdx.x;
    const int base = bbase[b];
    const int nE   = bbase[b + 1] - base;

    cnt[t] = 0;
    __syncthreads();
    for (int i = t; i < nE; i += 256)
        atomicAdd(&cnt[(bucketed[base + i].x >> 16) & 0xFF], 1);
    __syncthreads();
    sc[t] = cnt[t];
    __syncthreads();
    #pragma unroll
    for (int off = 1; off < 256; off <<= 1) {
        int u = (t >= off) ? sc[t - off] : 0;
        __syncthreads();
        sc[t] += u;
        __syncthreads();
    }
    const int ex = sc[t] - cnt[t];    // exclusive prefix within bucket
    lcur[t] = ex;
    __syncthreads();

    if (nE <= BUF_CAP) {
        for (int i = t; i < nE; i += 256) {
            const int2 e = bucketed[base + i];
            const int  n = (e.x >> 16) & 0xFF;
            const int  p = atomicAdd(&lcur[n], 1);
            buf[p] = make_int2(e.x & 0xFFFF, e.y);
        }
        __syncthreads();
        for (int i = t; i < nE; i += 256)
            packed[base + i] = buf[i];        // coalesced
    } else {
        // pathological overflow: direct (uncoalesced) global scatter
        for (int i = t; i < nE; i += 256) {
            const int2 e = bucketed[base + i];
            const int  n = (e.x >> 16) & 0xFF;
            const int  p = atomicAdd(&lcur[n], 1);
            packed[base + p] = make_int2(e.x & 0xFFFF, e.y);
        }
    }

    const int node = b * 256 + t;
    if (node < N_NODES) offs[node] = base + ex;
    if (b == N_BKT - 1 && t == 0) offs[N_NODES] = N_EDGES;
}

// ---------------------------------------------------------------------------
// SpMM gather (bf16 support): one wave per dst node, lane owns 2 dims.
// relu folded in; agg stored bf16 (feeds GEMM2 A-fragments directly).
// ---------------------------------------------------------------------------
__global__ __launch_bounds__(256) void csr_gather_bf16(
    const unsigned int* __restrict__ sup, const int2* __restrict__ packed,
    const int* __restrict__ offs, unsigned int* __restrict__ agg)
{
    const int node = (blockIdx.x * 256 + threadIdx.x) >> 6;
    const int lane = threadIdx.x & 63;
    if (node >= N_NODES) return;
    const int beg = offs[node];
    const int end = offs[node + 1];

    float ax = 0.f, ay = 0.f;
    int j = beg;
    for (; j + 3 < end; j += 4) {
        const int2 e0 = packed[j];
        const int2 e1 = packed[j + 1];
        const int2 e2 = packed[j + 2];
        const int2 e3 = packed[j + 3];
        const unsigned int u0 = sup[(size_t)e0.x * 64 + lane];
        const unsigned int u1 = sup[(size_t)e1.x * 64 + lane];
        const unsigned int u2 = sup[(size_t)e2.x * 64 + lane];
        const unsigned int u3 = sup[(size_t)e3.x * 64 + lane];
        const float v0 = __int_as_float(e0.y);
        const float v1 = __int_as_float(e1.y);
        const float v2 = __int_as_float(e2.y);
        const float v3 = __int_as_float(e3.y);
        ax += __uint_as_float(u0 << 16) * v0;          ay += __uint_as_float(u0 & 0xffff0000u) * v0;
        ax += __uint_as_float(u1 << 16) * v1;          ay += __uint_as_float(u1 & 0xffff0000u) * v1;
        ax += __uint_as_float(u2 << 16) * v2;          ay += __uint_as_float(u2 & 0xffff0000u) * v2;
        ax += __uint_as_float(u3 << 16) * v3;          ay += __uint_as_float(u3 & 0xffff0000u) * v3;
    }
    for (; j < end; ++j) {
        const int2 e0 = packed[j];
        const unsigned int u0 = sup[(size_t)e0.x * 64 + lane];
        const float v0 = __int_as_float(e0.y);
        ax += __uint_as_float(u0 << 16) * v0;
        ay += __uint_as_float(u0 & 0xffff0000u) * v0;
    }
    ax = fmaxf(ax, 0.f);
    ay = fmaxf(ay, 0.f);
    agg[(size_t)node * 64 + lane] = (unsigned int)f2bf(ax) | ((unsigned int)f2bf(ay) << 16);
}

// ---------------------------------------------------------------------------
// GEMM2 (MFMA, no LDS) + row L2-normalize: out = rownorm(agg @ W2^T + b2)
// ---------------------------------------------------------------------------
__global__ __launch_bounds__(256) void gemm2_mfma(
    const short8* __restrict__ aggv, const short8* __restrict__ Bp,
    const float* __restrict__ bias, float* __restrict__ out)
{
    const int wave  = threadIdx.x >> 6;
    const int lane  = threadIdx.x & 63;
    const int strip = blockIdx.x * 4 + wave;
    if (strip >= N_STRIPS) return;
    const int m = lane & 15;
    const int q = lane >> 4;
    const int row = strip * 16 + m;

    short8 a[4];
    #pragma unroll
    for (int ks = 0; ks < 4; ++ks)
        a[ks] = aggv[(size_t)row * (DIM / 8) + ks * 4 + q];

    floatx4 acc[8];
    #pragma unroll
    for (int nt = 0; nt < 8; ++nt) { acc[nt][0] = 0.f; acc[nt][1] = 0.f; acc[nt][2] = 0.f; acc[nt][3] = 0.f; }

    #pragma unroll
    for (int ks = 0; ks < 4; ++ks) {
        #pragma unroll
        for (int nt = 0; nt < 8; ++nt) {
            const short8 bf = Bp[(ks * 8 + nt) * 64 + lane];
            acc[nt] = __builtin_amdgcn_mfma_f32_16x16x32_bf16(a[ks], bf, acc[nt], 0, 0, 0);
        }
    }

    #pragma unroll
    for (int nt = 0; nt < 8; ++nt) {
        const float bb = bias[nt * 16 + m];
        #pragma unroll
        for (int i = 0; i < 4; ++i) acc[nt][i] += bb;
    }

    float sq[4] = {0.f, 0.f, 0.f, 0.f};
    #pragma unroll
    for (int nt = 0; nt < 8; ++nt)
        #pragma unroll
        for (int i = 0; i < 4; ++i) sq[i] += acc[nt][i] * acc[nt][i];
    #pragma unroll
    for (int i = 0; i < 4; ++i) {
        #pragma unroll
        for (int mask = 1; mask < 16; mask <<= 1)
            sq[i] += __shfl_xor(sq[i], mask);
        sq[i] = 1.0f / sqrtf(sq[i]);
    }

    #pragma unroll
    for (int nt = 0; nt < 8; ++nt) {
        #pragma unroll
        for (int i = 0; i < 4; ++i) {
            const int r = strip * 16 + q * 4 + i;
            out[(size_t)r * DIM + nt * 16 + m] = acc[nt][i] * sq[i];
        }
    }
}

// ---------------------------------------------------------------------------
extern "C" void kernel_launch(void* const* d_in, const int* in_sizes, int n_in,
                              void* d_out, int out_size, void* d_ws, size_t ws_size,
                              hipStream_t stream) {
    const float* x    = (const float*)d_in[0];
    const float* vals = (const float*)d_in[1];
    const float* W_gc = (const float*)d_in[2];
    const float* b_gc = (const float*)d_in[3];
    const float* W2   = (const float*)d_in[4];
    const float* b2   = (const float*)d_in[5];
    const int*   src  = (const int*)d_in[6];
    const int*   dst  = (const int*)d_in[7];

    // support (bf16, 12.8 MB) staged in d_out; final fp32 out overwrites it.
    unsigned short* support = (unsigned short*)d_out;
    float* out = (float*)d_out;

    // ws layout (all 16B-aligned)
    const size_t AGG_B  = (size_t)N_NODES * DIM * 2;   // 12,800,000 (bf16)
    const size_t OFFS_B = 200064;                      // offs[N+1]
    const size_t BKT_B  = 4096;                        // bcnt/bbase/gbcur (196 each)
    const size_t BUK_B  = (size_t)N_EDGES * 8;         // bucketed, 6.4 MB
    const size_t PACK_B = (size_t)N_EDGES * 8;         // packed, 6.4 MB
    const size_t PW_B   = 32768;

    char* wsb = (char*)d_ws;
    unsigned int* agg   = (unsigned int*)wsb;
    int*   offs   = (int*)(wsb + AGG_B);
    int*   bcnt   = (int*)(wsb + AGG_B + OFFS_B);
    int*   bbase  = bcnt + 256;                        // 197 used
    int*   gbcur  = bcnt + 512;
    int2*  bucketed = (int2*)(wsb + AGG_B + OFFS_B + BKT_B);
    int2*  packed   = (int2*)(wsb + AGG_B + OFFS_B + BKT_B + BUK_B);
    uint4* pw1    = (uint4*)(wsb + AGG_B + OFFS_B + BKT_B + BUK_B + PACK_B);
    uint4* pw2    = (uint4*)(wsb + AGG_B + OFFS_B + BKT_B + BUK_B + PACK_B + PW_B);

    const int gb = (N_STRIPS + 3) / 4;             // 782 gemm blocks

    // pack W and W2 into MFMA B-fragment order (bf16)
    pack_weights<<<16, 256, 0, stream>>>(W_gc, W2, pw1, pw2);

    // support = bf16(x @ W_gc + b_gc)
    gemm1_mfma<<<gb, 256, 0, stream>>>(x, (const short8*)pw1, b_gc, support);

    // CSR build: bucketed counting sort by dst
    hipMemsetAsync(bcnt, 0, 1024, stream);
    bucket_hist<<<EDGE_BLOCKS, 256, 0, stream>>>(dst, bcnt);
    scan_buckets<<<1, 256, 0, stream>>>(bcnt, bbase, gbcur);
    bucket_scatter<<<EDGE_BLOCKS, 256, 0, stream>>>(src, dst, vals, gbcur, bucketed);
    bucket_to_csr<<<N_BKT, 256, 0, stream>>>(bucketed, bbase, packed, offs);

    // agg = bf16(relu(segment_sum(support[src]*val, dst)))
    csr_gather_bf16<<<(N_NODES * 64 + 255) / 256, 256, 0, stream>>>(
        (const unsigned int*)support, packed, offs, agg);

    // out = rownorm(agg @ W2^T + b2)
    gemm2_mfma<<<gb, 256, 0, stream>>>(
        (const short8*)agg, (const short8*)pw2, b2, out);
}

// Round 6
// 180.966 us; speedup vs baseline: 8.2422x; 1.0592x over previous
//
#include <hip/hip_runtime.h>
#include <hip/hip_bf16.h>

#define N_NODES 50000
#define N_EDGES 800000
#define DIM     128
#define N_STRIPS (N_NODES / 16)               // 3125 exact: 16-row strips
#define N_BKT    ((N_NODES + 255) / 256)      // 196 buckets (dst >> 8)
#define EDGE_BLOCKS ((N_EDGES + 4095) / 4096) // 196 chunks of 4096 edges
#define BUF_CAP  6144                          // LDS edge buffer (mean 4082, 32 sigma)
#define GEMM_BLOCKS ((N_STRIPS + 3) / 4)      // 782
#define HIST_BLOCK0 GEMM_BLOCKS               // 782..978: hist chunks
#define PACK_BLOCK0 (GEMM_BLOCKS + EDGE_BLOCKS) // 978..994: weight pack
#define FRONT_BLOCKS (PACK_BLOCK0 + 16)       // 994

typedef short short8 __attribute__((ext_vector_type(8)));
typedef float floatx4 __attribute__((ext_vector_type(4)));

// fp32 -> bf16 (RNE) bit pattern
__device__ inline unsigned short f2bf(float f) {
    __hip_bfloat16 h = __float2bfloat16(f);
    return *reinterpret_cast<unsigned short*>(&h);
}

// ---------------------------------------------------------------------------
// Fused front end. Block ranges:
//  [0, 782):   GEMM1 (MFMA, no LDS): support = bf16(x @ W + b), 4 waves/block
//  [782, 978): per-chunk bucket histogram (bucket = dst>>8) -> blk_hist (no atomics)
//  [978, 994): pack W / W2 into MFMA B-fragment order (bf16)
// All three are data-independent -> co-scheduled in one dispatch.
// ---------------------------------------------------------------------------
__global__ __launch_bounds__(256) void fused_front(
    const float* __restrict__ x, const float* __restrict__ W,
    const float* __restrict__ W2, const float* __restrict__ bias,
    const int* __restrict__ dst,
    unsigned short* __restrict__ support, int* __restrict__ blk_hist,
    uint4* __restrict__ p1, uint4* __restrict__ p2)
{
    __shared__ int bh[256];
    const int t = threadIdx.x;

    if (blockIdx.x < HIST_BLOCK0) {
        // ---------------- GEMM1 ----------------
        const int wave  = t >> 6;
        const int lane  = t & 63;
        const int strip = blockIdx.x * 4 + wave;
        if (strip >= N_STRIPS) return;
        const int m = lane & 15;
        const int q = lane >> 4;
        const int row = strip * 16 + m;

        short8 a[4];
        const float4* xr = reinterpret_cast<const float4*>(&x[(size_t)row * DIM]);
        #pragma unroll
        for (int ks = 0; ks < 4; ++ks) {
            const float4 f0 = xr[ks * 8 + q * 2];
            const float4 f1 = xr[ks * 8 + q * 2 + 1];
            short8 tt;
            tt[0] = (short)f2bf(f0.x); tt[1] = (short)f2bf(f0.y);
            tt[2] = (short)f2bf(f0.z); tt[3] = (short)f2bf(f0.w);
            tt[4] = (short)f2bf(f1.x); tt[5] = (short)f2bf(f1.y);
            tt[6] = (short)f2bf(f1.z); tt[7] = (short)f2bf(f1.w);
            a[ks] = tt;
        }

        floatx4 acc[8];
        #pragma unroll
        for (int nt = 0; nt < 8; ++nt) { acc[nt][0]=0.f; acc[nt][1]=0.f; acc[nt][2]=0.f; acc[nt][3]=0.f; }

        const short8* Bp = (const short8*)p1;
        #pragma unroll
        for (int ks = 0; ks < 4; ++ks) {
            #pragma unroll
            for (int nt = 0; nt < 8; ++nt) {
                const short8 bf = Bp[(ks * 8 + nt) * 64 + lane];
                acc[nt] = __builtin_amdgcn_mfma_f32_16x16x32_bf16(a[ks], bf, acc[nt], 0, 0, 0);
            }
        }

        #pragma unroll
        for (int nt = 0; nt < 8; ++nt) {
            const float bb = bias[nt * 16 + m];
            #pragma unroll
            for (int i = 0; i < 4; ++i) {
                const int r = strip * 16 + q * 4 + i;
                support[(size_t)r * DIM + nt * 16 + m] = f2bf(acc[nt][i] + bb);
            }
        }
    } else if (blockIdx.x < PACK_BLOCK0) {
        // ---------------- blockwise bucket histogram ----------------
        const int chunk = blockIdx.x - HIST_BLOCK0;
        bh[t] = 0;
        __syncthreads();
        const int base   = chunk * 4096;
        const int navail = min(4096, N_EDGES - base);    // 4096 or 1280; both %4==0
        const int4* d4 = reinterpret_cast<const int4*>(dst + base);
        #pragma unroll
        for (int i = 0; i < 4; ++i) {
            const int j = t + i * 256;
            if (j * 4 < navail) {
                const int4 d = d4[j];
                atomicAdd(&bh[d.x >> 8], 1);
                atomicAdd(&bh[d.y >> 8], 1);
                atomicAdd(&bh[d.z >> 8], 1);
                atomicAdd(&bh[d.w >> 8], 1);
            }
        }
        __syncthreads();
        blk_hist[chunk * 256 + t] = bh[t];
    } else {
        // ---------------- weight pack ----------------
        const int pb   = blockIdx.x - PACK_BLOCK0;       // 0..15
        const int s    = (pb & 7) * 256 + t;             // 0..2047
        const int lane = s & 63;
        const int nt   = (s >> 6) & 7;
        const int ks   = s >> 9;
        const int m    = lane & 15;
        const int q    = lane >> 4;

        unsigned short e[8];
        if (pb < 8) {
            #pragma unroll
            for (int j = 0; j < 8; ++j)
                e[j] = f2bf(W[(ks * 32 + q * 8 + j) * DIM + nt * 16 + m]);
            uint4 o;
            o.x = (unsigned)e[0] | ((unsigned)e[1] << 16);
            o.y = (unsigned)e[2] | ((unsigned)e[3] << 16);
            o.z = (unsigned)e[4] | ((unsigned)e[5] << 16);
            o.w = (unsigned)e[6] | ((unsigned)e[7] << 16);
            p1[s] = o;
        } else {
            const float4 f0 = *reinterpret_cast<const float4*>(&W2[(nt * 16 + m) * DIM + ks * 32 + q * 8]);
            const float4 f1 = *reinterpret_cast<const float4*>(&W2[(nt * 16 + m) * DIM + ks * 32 + q * 8 + 4]);
            e[0] = f2bf(f0.x); e[1] = f2bf(f0.y); e[2] = f2bf(f0.z); e[3] = f2bf(f0.w);
            e[4] = f2bf(f1.x); e[5] = f2bf(f1.y); e[6] = f2bf(f1.z); e[7] = f2bf(f1.w);
            uint4 o;
            o.x = (unsigned)e[0] | ((unsigned)e[1] << 16);
            o.y = (unsigned)e[2] | ((unsigned)e[3] << 16);
            o.z = (unsigned)e[4] | ((unsigned)e[5] << 16);
            o.w = (unsigned)e[6] | ((unsigned)e[7] << 16);
            p2[s] = o;
        }
    }
}

// NOTE: gemm1 in fused_front reads p1 written by pack blocks of the SAME
// dispatch -- that would be a race. Fix: pack runs in a tiny prologue kernel
// for p1; fused_front packs only p2 (needed 4 dispatches later). See launch.

// Prologue: pack W only (p1), 8 blocks.
__global__ __launch_bounds__(256) void pack_w1(
    const float* __restrict__ W, uint4* __restrict__ p1)
{
    const int s    = blockIdx.x * 256 + threadIdx.x;     // 0..2047
    const int lane = s & 63;
    const int nt   = (s >> 6) & 7;
    const int ks   = s >> 9;
    const int m    = lane & 15;
    const int q    = lane >> 4;
    unsigned short e[8];
    #pragma unroll
    for (int j = 0; j < 8; ++j)
        e[j] = f2bf(W[(ks * 32 + q * 8 + j) * DIM + nt * 16 + m]);
    uint4 o;
    o.x = (unsigned)e[0] | ((unsigned)e[1] << 16);
    o.y = (unsigned)e[2] | ((unsigned)e[3] << 16);
    o.z = (unsigned)e[4] | ((unsigned)e[5] << 16);
    o.w = (unsigned)e[6] | ((unsigned)e[7] << 16);
    p1[s] = o;
}

// ---------------------------------------------------------------------------
// Scan per-chunk histograms -> per-chunk per-bucket scatter bases (blk_base)
// + bucket starts (bbase[197]). One block x 1024: 4 parts x 256 buckets.
// ---------------------------------------------------------------------------
__global__ __launch_bounds__(1024) void scan_hist(
    const int* __restrict__ blk_hist, int* __restrict__ blk_base,
    int* __restrict__ bbase)
{
    __shared__ int psum[4][256];
    __shared__ int stot[256];
    __shared__ int sinc[256];

    const int t    = threadIdx.x;
    const int b    = t & 255;
    const int part = t >> 8;
    const int c0   = part * 49;
    const int c1   = min(c0 + 49, EDGE_BLOCKS);

    int run = 0;
    #pragma unroll 7
    for (int c = c0; c < c1; ++c) {
        const int v = blk_hist[c * 256 + b];
        blk_base[c * 256 + b] = run;
        run += v;
    }
    psum[part][b] = run;
    __syncthreads();

    if (part == 0) {
        const int tot = psum[0][b] + psum[1][b] + psum[2][b] + psum[3][b];
        stot[b] = tot;
        sinc[b] = tot;
    }
    __syncthreads();
    // inclusive scan of sinc over 256 buckets (part 0 does work, all hit barriers)
    for (int off = 1; off < 256; off <<= 1) {
        int u = 0;
        if (part == 0 && b >= off) u = sinc[b - off];
        __syncthreads();
        if (part == 0 && b >= off) sinc[b] += u;
        __syncthreads();
    }
    const int ex = sinc[b] - stot[b];        // exclusive bucket base
    if (part == 0 && b < N_BKT) bbase[b] = ex;
    if (t == 0) bbase[N_BKT] = N_EDGES;

    int partbase = 0;
    #pragma unroll
    for (int p = 0; p < 4; ++p) if (p < part) partbase += psum[p][b];
    const int add = ex + partbase;
    #pragma unroll 7
    for (int c = c0; c < c1; ++c) blk_base[c * 256 + b] += add;
}

// ---------------------------------------------------------------------------
// Deterministic bucket scatter: bases precomputed per (chunk,bucket); only
// LDS atomics for within-chunk ordering. Writes land in contiguous runs.
// Payload: word0 = src | (dst&0xFF)<<16, word1 = val bits.
// ---------------------------------------------------------------------------
__global__ __launch_bounds__(256) void bucket_scatter(
    const int* __restrict__ src, const int* __restrict__ dst,
    const float* __restrict__ vals, const int* __restrict__ blk_base,
    int2* __restrict__ bucketed)
{
    __shared__ int rcur[256];
    const int t     = threadIdx.x;
    const int chunk = blockIdx.x;
    rcur[t] = blk_base[chunk * 256 + t];
    __syncthreads();

    const int base   = chunk * 4096;
    const int navail = min(4096, N_EDGES - base);
    const int4*   s4 = reinterpret_cast<const int4*>(src + base);
    const int4*   d4 = reinterpret_cast<const int4*>(dst + base);
    const float4* v4 = reinterpret_cast<const float4*>(vals + base);
    #pragma unroll
    for (int i = 0; i < 4; ++i) {
        const int j = t + i * 256;
        if (j * 4 < navail) {
            const int4   s = s4[j];
            const int4   d = d4[j];
            const float4 v = v4[j];
            int p;
            p = atomicAdd(&rcur[d.x >> 8], 1);
            bucketed[p] = make_int2((s.x & 0xFFFF) | ((d.x & 0xFF) << 16), __float_as_int(v.x));
            p = atomicAdd(&rcur[d.y >> 8], 1);
            bucketed[p] = make_int2((s.y & 0xFFFF) | ((d.y & 0xFF) << 16), __float_as_int(v.y));
            p = atomicAdd(&rcur[d.z >> 8], 1);
            bucketed[p] = make_int2((s.z & 0xFFFF) | ((d.z & 0xFF) << 16), __float_as_int(v.z));
            p = atomicAdd(&rcur[d.w >> 8], 1);
            bucketed[p] = make_int2((s.w & 0xFFFF) | ((d.w & 0xFF) << 16), __float_as_int(v.w));
        }
    }
}

// ---------------------------------------------------------------------------
// One block per bucket: per-node LDS count + scan, LDS scatter, coalesced
// linear write to packed; emits offs.
// ---------------------------------------------------------------------------
__global__ __launch_bounds__(256) void bucket_to_csr(
    const int2* __restrict__ bucketed, const int* __restrict__ bbase,
    int2* __restrict__ packed, int* __restrict__ offs)
{
    __shared__ int cnt[256];
    __shared__ int sc[256];
    __shared__ int lcur[256];
    __shared__ int2 buf[BUF_CAP];

    const int b    = blockIdx.x;
    const int t    = threadIdx.x;
    const int base = bbase[b];
    const int nE   = bbase[b + 1] - base;

    cnt[t] = 0;
    __syncthreads();
    for (int i = t; i < nE; i += 256)
        atomicAdd(&cnt[(bucketed[base + i].x >> 16) & 0xFF], 1);
    __syncthreads();
    sc[t] = cnt[t];
    __syncthreads();
    #pragma unroll
    for (int off = 1; off < 256; off <<= 1) {
        int u = (t >= off) ? sc[t - off] : 0;
        __syncthreads();
        sc[t] += u;
        __syncthreads();
    }
    const int ex = sc[t] - cnt[t];
    lcur[t] = ex;
    __syncthreads();

    if (nE <= BUF_CAP) {
        for (int i = t; i < nE; i += 256) {
            const int2 e = bucketed[base + i];
            const int  n = (e.x >> 16) & 0xFF;
            const int  p = atomicAdd(&lcur[n], 1);
            buf[p] = make_int2(e.x & 0xFFFF, e.y);
        }
        __syncthreads();
        for (int i = t; i < nE; i += 256)
            packed[base + i] = buf[i];
    } else {
        for (int i = t; i < nE; i += 256) {
            const int2 e = bucketed[base + i];
            const int  n = (e.x >> 16) & 0xFF;
            const int  p = atomicAdd(&lcur[n], 1);
            packed[base + p] = make_int2(e.x & 0xFFFF, e.y);
        }
    }

    const int node = b * 256 + t;
    if (node < N_NODES) offs[node] = base + ex;
    if (b == N_BKT - 1 && t == 0) offs[N_NODES] = N_EDGES;
}

// ---------------------------------------------------------------------------
// SpMM gather (bf16 support): one wave per dst node, lane owns 2 dims.
// relu folded in; agg stored bf16 (feeds GEMM2 A-fragments directly).
// ---------------------------------------------------------------------------
__global__ __launch_bounds__(256) void csr_gather_bf16(
    const unsigned int* __restrict__ sup, const int2* __restrict__ packed,
    const int* __restrict__ offs, unsigned int* __restrict__ agg)
{
    const int node = (blockIdx.x * 256 + threadIdx.x) >> 6;
    const int lane = threadIdx.x & 63;
    if (node >= N_NODES) return;
    const int beg = offs[node];
    const int end = offs[node + 1];

    float ax = 0.f, ay = 0.f;
    int j = beg;
    for (; j + 3 < end; j += 4) {
        const int2 e0 = packed[j];
        const int2 e1 = packed[j + 1];
        const int2 e2 = packed[j + 2];
        const int2 e3 = packed[j + 3];
        const unsigned int u0 = sup[(size_t)e0.x * 64 + lane];
        const unsigned int u1 = sup[(size_t)e1.x * 64 + lane];
        const unsigned int u2 = sup[(size_t)e2.x * 64 + lane];
        const unsigned int u3 = sup[(size_t)e3.x * 64 + lane];
        const float v0 = __int_as_float(e0.y);
        const float v1 = __int_as_float(e1.y);
        const float v2 = __int_as_float(e2.y);
        const float v3 = __int_as_float(e3.y);
        ax += __uint_as_float(u0 << 16) * v0;          ay += __uint_as_float(u0 & 0xffff0000u) * v0;
        ax += __uint_as_float(u1 << 16) * v1;          ay += __uint_as_float(u1 & 0xffff0000u) * v1;
        ax += __uint_as_float(u2 << 16) * v2;          ay += __uint_as_float(u2 & 0xffff0000u) * v2;
        ax += __uint_as_float(u3 << 16) * v3;          ay += __uint_as_float(u3 & 0xffff0000u) * v3;
    }
    for (; j < end; ++j) {
        const int2 e0 = packed[j];
        const unsigned int u0 = sup[(size_t)e0.x * 64 + lane];
        const float v0 = __int_as_float(e0.y);
        ax += __uint_as_float(u0 << 16) * v0;
        ay += __uint_as_float(u0 & 0xffff0000u) * v0;
    }
    ax = fmaxf(ax, 0.f);
    ay = fmaxf(ay, 0.f);
    agg[(size_t)node * 64 + lane] = (unsigned int)f2bf(ax) | ((unsigned int)f2bf(ay) << 16);
}

// ---------------------------------------------------------------------------
// GEMM2 (MFMA, no LDS) + row L2-normalize: out = rownorm(agg @ W2^T + b2)
// ---------------------------------------------------------------------------
__global__ __launch_bounds__(256) void gemm2_mfma(
    const short8* __restrict__ aggv, const short8* __restrict__ Bp,
    const float* __restrict__ bias, float* __restrict__ out)
{
    const int wave  = threadIdx.x >> 6;
    const int lane  = threadIdx.x & 63;
    const int strip = blockIdx.x * 4 + wave;
    if (strip >= N_STRIPS) return;
    const int m = lane & 15;
    const int q = lane >> 4;
    const int row = strip * 16 + m;

    short8 a[4];
    #pragma unroll
    for (int ks = 0; ks < 4; ++ks)
        a[ks] = aggv[(size_t)row * (DIM / 8) + ks * 4 + q];

    floatx4 acc[8];
    #pragma unroll
    for (int nt = 0; nt < 8; ++nt) { acc[nt][0]=0.f; acc[nt][1]=0.f; acc[nt][2]=0.f; acc[nt][3]=0.f; }

    #pragma unroll
    for (int ks = 0; ks < 4; ++ks) {
        #pragma unroll
        for (int nt = 0; nt < 8; ++nt) {
            const short8 bf = Bp[(ks * 8 + nt) * 64 + lane];
            acc[nt] = __builtin_amdgcn_mfma_f32_16x16x32_bf16(a[ks], bf, acc[nt], 0, 0, 0);
        }
    }

    #pragma unroll
    for (int nt = 0; nt < 8; ++nt) {
        const float bb = bias[nt * 16 + m];
        #pragma unroll
        for (int i = 0; i < 4; ++i) acc[nt][i] += bb;
    }

    float sq[4] = {0.f, 0.f, 0.f, 0.f};
    #pragma unroll
    for (int nt = 0; nt < 8; ++nt)
        #pragma unroll
        for (int i = 0; i < 4; ++i) sq[i] += acc[nt][i] * acc[nt][i];
    #pragma unroll
    for (int i = 0; i < 4; ++i) {
        #pragma unroll
        for (int mask = 1; mask < 16; mask <<= 1)
            sq[i] += __shfl_xor(sq[i], mask);
        sq[i] = 1.0f / sqrtf(sq[i]);
    }

    #pragma unroll
    for (int nt = 0; nt < 8; ++nt) {
        #pragma unroll
        for (int i = 0; i < 4; ++i) {
            const int r = strip * 16 + q * 4 + i;
            out[(size_t)r * DIM + nt * 16 + m] = acc[nt][i] * sq[i];
        }
    }
}

// ---------------------------------------------------------------------------
extern "C" void kernel_launch(void* const* d_in, const int* in_sizes, int n_in,
                              void* d_out, int out_size, void* d_ws, size_t ws_size,
                              hipStream_t stream) {
    const float* x    = (const float*)d_in[0];
    const float* vals = (const float*)d_in[1];
    const float* W_gc = (const float*)d_in[2];
    const float* b_gc = (const float*)d_in[3];
    const float* W2   = (const float*)d_in[4];
    const float* b2   = (const float*)d_in[5];
    const int*   src  = (const int*)d_in[6];
    const int*   dst  = (const int*)d_in[7];

    unsigned short* support = (unsigned short*)d_out;   // bf16 staging in d_out
    float* out = (float*)d_out;

    // ws layout (all 16B-aligned)
    const size_t AGG_B  = (size_t)N_NODES * DIM * 2;   // 12,800,000 (bf16)
    const size_t OFFS_B = 200064;                      // offs[N+1]
    const size_t BH_B   = (size_t)EDGE_BLOCKS * 256 * 4;  // blk_hist 200,704
    const size_t BB_B   = (size_t)EDGE_BLOCKS * 256 * 4;  // blk_base 200,704
    const size_t BKT_B  = 1024;                        // bbase[197]
    const size_t BUK_B  = (size_t)N_EDGES * 8;         // bucketed 6.4 MB
    const size_t PACK_B = (size_t)N_EDGES * 8;         // packed 6.4 MB
    const size_t PW_B   = 32768;

    char* wsb = (char*)d_ws;
    unsigned int* agg = (unsigned int*)wsb;
    int*   offs     = (int*)(wsb + AGG_B);
    int*   blk_hist = (int*)(wsb + AGG_B + OFFS_B);
    int*   blk_base = (int*)(wsb + AGG_B + OFFS_B + BH_B);
    int*   bbase    = (int*)(wsb + AGG_B + OFFS_B + BH_B + BB_B);
    int2*  bucketed = (int2*)(wsb + AGG_B + OFFS_B + BH_B + BB_B + BKT_B);
    int2*  packed   = (int2*)(wsb + AGG_B + OFFS_B + BH_B + BB_B + BKT_B + BUK_B);
    uint4* pw1      = (uint4*)(wsb + AGG_B + OFFS_B + BH_B + BB_B + BKT_B + BUK_B + PACK_B);
    uint4* pw2      = (uint4*)(wsb + AGG_B + OFFS_B + BH_B + BB_B + BKT_B + BUK_B + PACK_B + PW_B);

    // 1. pack W -> pw1 (gemm1's B; must precede fused_front)
    pack_w1<<<8, 256, 0, stream>>>(W_gc, pw1);

    // 2. fused: gemm1 || blockwise hist || pack W2 -> pw2
    fused_front<<<FRONT_BLOCKS, 256, 0, stream>>>(
        x, W_gc, W2, b_gc, dst, support, blk_hist, pw1, pw2);

    // 3. scan histograms -> per-chunk bases + bucket starts
    scan_hist<<<1, 1024, 0, stream>>>(blk_hist, blk_base, bbase);

    // 4. deterministic bucket scatter
    bucket_scatter<<<EDGE_BLOCKS, 256, 0, stream>>>(src, dst, vals, blk_base, bucketed);

    // 5. bucket -> CSR (packed, offs)
    bucket_to_csr<<<N_BKT, 256, 0, stream>>>(bucketed, bbase, packed, offs);

    // 6. agg = bf16(relu(segment_sum(support[src]*val, dst)))
    csr_gather_bf16<<<(N_NODES * 64 + 255) / 256, 256, 0, stream>>>(
        (const unsigned int*)support, packed, offs, agg);

    // 7. out = rownorm(agg @ W2^T + b2)
    gemm2_mfma<<<(N_STRIPS + 3) / 4, 256, 0, stream>>>(
        (const short8*)agg, (const short8*)pw2, b2, out);
}